// Round 5
// baseline (441.624 us; speedup 1.0000x reference)
//
#include <hip/hip_runtime.h>
#include <math.h>

typedef unsigned short u16;
typedef __attribute__((ext_vector_type(8))) short short8;
typedef __attribute__((ext_vector_type(4))) float floatx4;
typedef __attribute__((ext_vector_type(4))) short sh4v;

union sh4u { sh4v v; u16 u[4]; };
union sh8u { short8 v; u16 u[8]; };

__device__ __forceinline__ floatx4 mfma16(short8 a, short8 b, floatx4 c) {
  return __builtin_amdgcn_mfma_f32_16x16x32_bf16(a, b, c, 0, 0, 0);
}

__device__ __forceinline__ floatx4 zero4() {
  floatx4 z = {0.f, 0.f, 0.f, 0.f};
  return z;
}

__device__ __forceinline__ u16 f2b(float f) {
  union { float f; unsigned u; } v; v.f = f;
  unsigned u = v.u;
  return (u16)((u + 0x7FFFu + ((u >> 16) & 1u)) >> 16);
}

__device__ __forceinline__ float b2f(u16 u) {
  union { unsigned u; float f; } v; v.u = ((unsigned)u) << 16;
  return v.f;
}

__device__ __forceinline__ float gelu_exact(float x) {
  return 0.5f * x * (1.f + erff(x * 0.70710678118654752440f));
}

__device__ __forceinline__ unsigned pack2(float a, float b) {
  return (unsigned)f2b(a) | ((unsigned)f2b(b) << 16);
}

// truncating pack of two f32 -> two bf16 in one v_perm
__device__ __forceinline__ unsigned permpack(float p0, float p1) {
  return __builtin_amdgcn_perm(__float_as_uint(p1), __float_as_uint(p0), 0x07060302u);
}

// ------------- weight prep: transpose-convert 6 weights + wcT build, one launch -------------
__global__ __launch_bounds__(256) void tc7_kernel(
    const float* __restrict__ p0, const float* __restrict__ p1,
    const float* __restrict__ p2, const float* __restrict__ p3,
    const float* __restrict__ p4, const float* __restrict__ p5,
    const float* __restrict__ wknn,
    u16* __restrict__ o0, u16* __restrict__ o1, u16* __restrict__ o2,
    u16* __restrict__ o3, u16* __restrict__ o4, u16* __restrict__ o5,
    u16* __restrict__ wcT) {
  __shared__ u16 L[64][66];
  int t = blockIdx.x, tid = threadIdx.x;
  if (t >= 540) {
    t -= 540;                       // 6 k-tiles x 12 j-tiles
    int tk = t / 12, tn = t % 12;
    int k0 = tk * 64, j0 = tn * 64;
#pragma unroll
    for (int i = 0; i < 4; i++) {
      int c = tid + 256 * i;
      int r = c >> 4, c4 = (c & 15) * 4;
      floatx4 v;
      if (j0 < 384) {
        v = *(const floatx4*)(wknn + (size_t)(k0 + r) * 384 + j0 + c4);
      } else {
        floatx4 a = *(const floatx4*)(wknn + (size_t)(384 + k0 + r) * 384 + (j0 - 384) + c4);
        floatx4 b = *(const floatx4*)(wknn + (size_t)(k0 + r) * 384 + (j0 - 384) + c4);
        v = a - b;
      }
      *(unsigned*)&L[r][c4]     = pack2(v[0], v[1]);
      *(unsigned*)&L[r][c4 + 2] = pack2(v[2], v[3]);
    }
    __syncthreads();
#pragma unroll
    for (int i = 0; i < 2; i++) {
      int c = tid + 256 * i;
      int nn = c >> 3, k8 = (c & 7) * 8;
      sh8u pk;
#pragma unroll
      for (int j = 0; j < 8; j++) pk.u[j] = L[k8 + j][nn];
      *(short8*)(wcT + (size_t)(j0 + nn) * 384 + k0 + k8) = pk.v;
    }
    return;
  }
  const float* src; u16* dst; int Kd, Nd, tk, tn;
  if      (t < 108) { src = p0; dst = o0; Kd = 384;  Nd = 1152; tk = t / 18; tn = t % 18; }
  else if (t < 144) { src = p1; dst = o1; Kd = 384;  Nd = 384;  t -= 108; tk = t / 6;  tn = t % 6; }
  else if (t < 216) { src = p2; dst = o2; Kd = 768;  Nd = 384;  t -= 144; tk = t / 6;  tn = t % 6; }
  else if (t < 252) { src = p3; dst = o3; Kd = 384;  Nd = 384;  t -= 216; tk = t / 6;  tn = t % 6; }
  else if (t < 396) { src = p4; dst = o4; Kd = 384;  Nd = 1536; t -= 252; tk = t / 24; tn = t % 24; }
  else              { src = p5; dst = o5; Kd = 1536; Nd = 384;  t -= 396; tk = t / 6;  tn = t % 6; }
  int k0 = tk * 64, n0 = tn * 64;
#pragma unroll
  for (int i = 0; i < 4; i++) {
    int c = tid + 256 * i;
    int r = c >> 4, c4 = (c & 15) * 4;
    floatx4 v = *(const floatx4*)(src + (size_t)(k0 + r) * Nd + n0 + c4);
    *(unsigned*)&L[r][c4]     = pack2(v[0], v[1]);
    *(unsigned*)&L[r][c4 + 2] = pack2(v[2], v[3]);
  }
  __syncthreads();
#pragma unroll
  for (int i = 0; i < 2; i++) {
    int c = tid + 256 * i;
    int nn = c >> 3, k8 = (c & 7) * 8;
    sh8u pk;
#pragma unroll
    for (int j = 0; j < 8; j++) pk.u[j] = L[k8 + j][nn];
    *(short8*)(dst + (size_t)(n0 + nn) * Kd + k0 + k8) = pk.v;
  }
}

// ---------------- LayerNorm (fp32 in -> bf16 out), one wave per row of 384 ----------------
__global__ __launch_bounds__(256) void ln_kernel(const float* __restrict__ x,
                                                 const float* __restrict__ g,
                                                 const float* __restrict__ bia,
                                                 u16* __restrict__ out) {
  int wave = threadIdx.x >> 6, lane = threadIdx.x & 63;
  int row = blockIdx.x * 4 + wave;
  const float* xr = x + (size_t)row * 384;
  float v[6];
  float s = 0.f;
#pragma unroll
  for (int j = 0; j < 6; j++) { v[j] = xr[lane + 64 * j]; s += v[j]; }
#pragma unroll
  for (int off = 32; off > 0; off >>= 1) s += __shfl_xor(s, off);
  float mu = s * (1.f / 384.f);
  float ss = 0.f;
#pragma unroll
  for (int j = 0; j < 6; j++) { float d = v[j] - mu; ss += d * d; }
#pragma unroll
  for (int off = 32; off > 0; off >>= 1) ss += __shfl_xor(ss, off);
  float rstd = rsqrtf(ss * (1.f / 384.f) + 1e-5f);
  u16* orow = out + (size_t)row * 384;
#pragma unroll
  for (int j = 0; j < 6; j++) {
    int d = lane + 64 * j;
    orow[d] = f2b((v[j] - mu) * rstd * g[d] + bia[d]);
  }
}

// ---------------- gemm128: 128x128 tile, BK=64, B pre-transposed, optional A concat ----------------
// EPI: 0 bf16 | 2 +bias -> bf16 | 3 gelu(+bias) -> bf16 | 4 gate -> f32
//      5 +bias+resid -> f32 | 6 bf16 + Q pre-scale + V^T scatter (qkv)
template <int EPI>
__global__ __launch_bounds__(256) void gemm128_kernel(
    const u16* __restrict__ A0, const u16* __restrict__ A1, int Ksplit,
    const u16* __restrict__ BwT, int N, int K,
    const float* __restrict__ bias,
    float* __restrict__ outF, u16* __restrict__ outB,
    const u16* __restrict__ eA16, const u16* __restrict__ eK16,
    const float* __restrict__ eX, u16* __restrict__ outV) {
  __shared__ u16 As[128][72];
  __shared__ u16 Bs[128][72];
  int tid = threadIdx.x;
  int lane = tid & 63, wave = tid >> 6, quad = lane >> 4, l16 = lane & 15;
  int n0 = blockIdx.x * 128, m0 = blockIdx.y * 128;
  int wm = (wave >> 1) * 64, wn = (wave & 1) * 64;
  floatx4 acc[4][4];
#pragma unroll
  for (int i = 0; i < 4; i++)
#pragma unroll
    for (int j = 0; j < 4; j++) acc[i][j] = zero4();

  for (int k0 = 0; k0 < K; k0 += 64) {
    const u16* Ap;
    int kk, sA;
    if (k0 < Ksplit) { Ap = A0; kk = k0; sA = Ksplit; }
    else             { Ap = A1; kk = k0 - Ksplit; sA = K - Ksplit; }
#pragma unroll
    for (int i = 0; i < 4; i++) {
      int c = tid + 256 * i;
      int row = c >> 3, c8 = (c & 7) * 8;
      *(short8*)&As[row][c8] =
          *(const short8*)(Ap + (size_t)(m0 + row) * sA + kk + c8);
      *(short8*)&Bs[row][c8] =
          *(const short8*)(BwT + (size_t)(n0 + row) * K + k0 + c8);
    }
    __syncthreads();
#pragma unroll
    for (int kh = 0; kh < 2; kh++) {
      short8 af[4], bfr[4];
#pragma unroll
      for (int ti = 0; ti < 4; ti++)
        af[ti] = *(const short8*)&As[wm + ti * 16 + l16][kh * 32 + quad * 8];
#pragma unroll
      for (int tj = 0; tj < 4; tj++)
        bfr[tj] = *(const short8*)&Bs[wn + tj * 16 + l16][kh * 32 + quad * 8];
#pragma unroll
      for (int ti = 0; ti < 4; ti++)
#pragma unroll
        for (int tj = 0; tj < 4; tj++)
          acc[ti][tj] = mfma16(af[ti], bfr[tj], acc[ti][tj]);
    }
    __syncthreads();
  }

#pragma unroll
  for (int ti = 0; ti < 4; ti++)
#pragma unroll
    for (int tj = 0; tj < 4; tj++) {
      int col = n0 + wn + tj * 16 + l16;
      int row0 = m0 + wm + ti * 16 + quad * 4;
      if (EPI == 6) {
        float sc = (col < 384) ? 0.18033688011112042f : 1.f;  // Q * 0.125*log2(e)
        sh4u pk;
#pragma unroll
        for (int r = 0; r < 4; r++) {
          u16 bv = f2b(acc[ti][tj][r] * sc);
          outB[(size_t)(row0 + r) * N + col] = bv;
          pk.u[r] = bv;
        }
        if (col >= 768) {
          int b = row0 >> 11, n = row0 & 2047;
          int hd = col - 768;
          *(sh4v*)(outV + ((size_t)(b * 6 + (hd >> 6)) * 64 + (hd & 63)) * 2048 + n) = pk.v;
        }
      } else {
#pragma unroll
        for (int r = 0; r < 4; r++) {
          size_t rc = (size_t)(row0 + r) * N + col;
          float v = acc[ti][tj][r];
          if (EPI == 0) {
            outB[rc] = f2b(v);
          } else if (EPI == 2) {
            outB[rc] = f2b(v + bias[col]);
          } else if (EPI == 3) {
            outB[rc] = f2b(gelu_exact(v + bias[col]));
          } else if (EPI == 4) {
            float gte = 1.f / (1.f + __expf(-(v + bias[col])));
            float fu = (1.f - gte) * b2f(eA16[rc]) + gte * b2f(eK16[rc]);
            outF[rc] = eX[rc] + fu;
          } else if (EPI == 5) {
            outF[rc] = v + bias[col] + eX[rc];
          }
        }
      }
    }
}

// ---------------- attention: direct-global K/V frags, no barriers, key-split=2 ----------------
// grid (32 qblocks, 24 bh, 2 splits), 256 thr. Q pre-scaled by 0.125*log2e -> p = exp2(s).
// S^T = K.Q^T (A=K-frag from global, B=Q regs); P via per-wave LDS transform; O^T = V^T.P^T.
__global__ __launch_bounds__(256) void attn1_kernel(const u16* __restrict__ qkv,
                                                    const u16* __restrict__ Vt,
                                                    float* __restrict__ OP,
                                                    float* __restrict__ LS) {
  __shared__ u16 Ps[4][16][72];   // per-wave P [qrow][key]
  int tid = threadIdx.x;
  int lane = tid & 63, wave = tid >> 6, quad = lane >> 4, l16 = lane & 15;
  int bh = blockIdx.y, b = bh / 6, h = bh % 6;
  int q0 = blockIdx.x * 64, split = blockIdx.z;
  const u16* qbase = qkv + (size_t)b * 2048 * 1152 + h * 64;
  const u16* kbase = qbase + 384;
  const u16* vtb = Vt + (size_t)bh * 64 * 2048;
  int qrow = q0 + wave * 16 + l16;
  short8 qf0 = *(const short8*)(qbase + (size_t)qrow * 1152 + quad * 8);
  short8 qf1 = *(const short8*)(qbase + (size_t)qrow * 1152 + 32 + quad * 8);
  floatx4 O[4];
  float lsum = 0.f;
#pragma unroll
  for (int j = 0; j < 4; j++) O[j] = zero4();

  // K-frag addresses: row key0+mt*16+l16, cols quad*8 / 32+quad*8
  const u16* krow = kbase + (size_t)(split * 1024 + l16) * 1152 + quad * 8;
  const u16* vrow = vtb + (size_t)l16 * 2048 + split * 1024 + quad * 8;
  short8 kf[8];
#pragma unroll
  for (int mt = 0; mt < 4; mt++) {
    kf[2 * mt]     = *(const short8*)(krow + (size_t)mt * 16 * 1152);
    kf[2 * mt + 1] = *(const short8*)(krow + (size_t)mt * 16 * 1152 + 32);
  }
  for (int kt = 0; kt < 16; kt++) {
    // S^T from prefetched K-frags
    floatx4 st[4];
#pragma unroll
    for (int mt = 0; mt < 4; mt++) {
      st[mt] = mfma16(kf[2 * mt], qf0, zero4());
      st[mt] = mfma16(kf[2 * mt + 1], qf1, st[mt]);
    }
    // V-frags for this tile (latency hidden behind exp/pack below)
    short8 vf[8];
#pragma unroll
    for (int mt2 = 0; mt2 < 4; mt2++) {
      const u16* vr = vrow + (size_t)mt2 * 16 * 2048 + kt * 64;
      vf[2 * mt2]     = *(const short8*)(vr);
      vf[2 * mt2 + 1] = *(const short8*)(vr + 32);
    }
    // softmax: p = exp2(s); pack 4 contiguous keys -> one b64 write
#pragma unroll
    for (int mt = 0; mt < 4; mt++) {
      float p0 = exp2f(st[mt][0]), p1 = exp2f(st[mt][1]);
      float p2 = exp2f(st[mt][2]), p3 = exp2f(st[mt][3]);
      lsum += (p0 + p1) + (p2 + p3);
      uint2 pk;
      pk.x = permpack(p0, p1);
      pk.y = permpack(p2, p3);
      *(uint2*)&Ps[wave][l16][mt * 16 + quad * 4] = pk;
    }
    // prefetch next tile's K-frags (consumed next iteration)
    if (kt < 15) {
      const u16* kr = krow + (size_t)(kt + 1) * 64 * 1152;
#pragma unroll
      for (int mt = 0; mt < 4; mt++) {
        kf[2 * mt]     = *(const short8*)(kr + (size_t)mt * 16 * 1152);
        kf[2 * mt + 1] = *(const short8*)(kr + (size_t)mt * 16 * 1152 + 32);
      }
    }
    // P^T as B-operand (intra-wave LDS round-trip, no barrier)
    short8 pf0 = *(const short8*)&Ps[wave][l16][quad * 8];
    short8 pf1 = *(const short8*)&Ps[wave][l16][32 + quad * 8];
#pragma unroll
    for (int mt2 = 0; mt2 < 4; mt2++) {
      O[mt2] = mfma16(vf[2 * mt2], pf0, O[mt2]);
      O[mt2] = mfma16(vf[2 * mt2 + 1], pf1, O[mt2]);
    }
  }
  lsum += __shfl_xor(lsum, 16);
  lsum += __shfl_xor(lsum, 32);
  int row = b * 2048 + q0 + wave * 16 + l16;
  float* op = OP + (size_t)split * 8192 * 384 + (size_t)row * 384 + h * 64;
#pragma unroll
  for (int mt2 = 0; mt2 < 4; mt2++)
    *(floatx4*)(op + mt2 * 16 + quad * 4) = O[mt2];
  if (quad == 0) LS[split * 8192 + row] = lsum;
}

// ---------------- attention combine: (O0+O1)/(l0+l1) -> bf16 ----------------
__global__ __launch_bounds__(256) void attn2_kernel(const float* __restrict__ OP,
                                                    const float* __restrict__ LS,
                                                    u16* __restrict__ attnpre) {
  int idx = blockIdx.x * 256 + threadIdx.x;  // 8192*96
  int row = idx / 96, c4 = (idx % 96) * 4;
  float rl = 1.f / (LS[row] + LS[8192 + row]);
  const float* o0 = OP + (size_t)row * 384 + c4;
  floatx4 a = *(const floatx4*)o0;
  floatx4 bv = *(const floatx4*)(o0 + (size_t)8192 * 384);
  sh4u pk;
#pragma unroll
  for (int j = 0; j < 4; j++) pk.u[j] = f2b((a[j] + bv[j]) * rl);
  *(sh4v*)(attnpre + (size_t)row * 384 + c4) = pk.v;
}

// ---------------- EdgeConv gather (bf16 G|base) + leaky-relu + max over K=8 ----------------
__global__ __launch_bounds__(256) void knn_kernel(const u16* __restrict__ GBb,
                                                  const int* __restrict__ idx,
                                                  const float* __restrict__ bknn,
                                                  u16* __restrict__ outB) {
  int wave = threadIdx.x >> 6, lane = threadIdx.x & 63;
  int row = blockIdx.x * 4 + wave;  // 0..8191
  int b = row >> 11, n = row & 2047;
  float base[6], acc[6];
#pragma unroll
  for (int j = 0; j < 6; j++) {
    int d = lane + 64 * j;
    base[j] = b2f(GBb[(size_t)row * 768 + 384 + d]) + bknn[d];
    acc[j] = -1e30f;
  }
  for (int kk = 0; kk < 8; kk++) {
    int g = idx[(b * 8 + kk) * 2048 + n];
    const u16* Gr = GBb + (size_t)g * 768;
#pragma unroll
    for (int j = 0; j < 6; j++) {
      float v = b2f(Gr[lane + 64 * j]) + base[j];
      v = v > 0.f ? v : 0.2f * v;
      acc[j] = fmaxf(acc[j], v);
    }
  }
#pragma unroll
  for (int j = 0; j < 6; j++)
    outB[(size_t)row * 384 + lane + 64 * j] = f2b(acc[j]);
}

// ---------------- launch ----------------
extern "C" void kernel_launch(void* const* d_in, const int* in_sizes, int n_in,
                              void* d_out, int out_size, void* d_ws, size_t ws_size,
                              hipStream_t stream) {
  const float* x    = (const float*)d_in[0];
  const int* kidx   = (const int*)d_in[1];
  const float* ln1g = (const float*)d_in[2];
  const float* ln1b = (const float*)d_in[3];
  const float* wqkv = (const float*)d_in[4];
  const float* wproj= (const float*)d_in[5];
  const float* bproj= (const float*)d_in[6];
  const float* wknn = (const float*)d_in[7];
  const float* bknn = (const float*)d_in[8];
  const float* wg1  = (const float*)d_in[9];
  const float* bg1  = (const float*)d_in[10];
  const float* wg2  = (const float*)d_in[11];
  const float* bg2  = (const float*)d_in[12];
  const float* ln2g = (const float*)d_in[13];
  const float* ln2b = (const float*)d_in[14];
  const float* wfc1 = (const float*)d_in[15];
  const float* bfc1 = (const float*)d_in[16];
  const float* wfc2 = (const float*)d_in[17];
  const float* bfc2 = (const float*)d_in[18];
  float* out = (float*)d_out;

  const int M = 8192;
  char* ws = (char*)d_ws;
  size_t off = 0;
  auto alloc = [&](size_t bytes) -> char* {
    char* p = ws + off;
    off += (bytes + 255) & ~(size_t)255;
    return p;
  };
  u16* nx_bf    = (u16*)alloc((size_t)M * 384 * 2);
  u16* qkv_bf   = (u16*)alloc((size_t)M * 1152 * 2);   // + attnpre reused as h_bf
  u16* attnpre  = (u16*)alloc((size_t)M * 384 * 2);
  u16* attn_bf  = (u16*)alloc((size_t)M * 384 * 2);
  u16* GBb      = (u16*)alloc((size_t)M * 768 * 2);    // [G | base] bf16
  u16* knn_bf   = (u16*)alloc((size_t)M * 384 * 2);
  float* x2     = (float*)alloc((size_t)M * 384 * 4);
  u16* t1_bf    = (u16*)alloc((size_t)M * 384 * 2);
  u16* nx2_bf   = (u16*)alloc((size_t)M * 384 * 2);
  u16* Vt_b     = (u16*)alloc((size_t)24 * 64 * 2048 * 2);
  u16* wqkvT    = (u16*)alloc((size_t)1152 * 384 * 2);
  u16* wprojT   = (u16*)alloc(384 * 384 * 2);
  u16* wcT      = (u16*)alloc((size_t)768 * 384 * 2);
  u16* wg1T     = (u16*)alloc((size_t)384 * 768 * 2);
  u16* wg2T     = (u16*)alloc(384 * 384 * 2);
  u16* wfc1T    = (u16*)alloc((size_t)1536 * 384 * 2);
  u16* wfc2T    = (u16*)alloc((size_t)384 * 1536 * 2);
  float* OP     = (float*)alloc((size_t)2 * M * 384 * 4);
  float* LS     = (float*)alloc((size_t)2 * M * 4);
  u16* h_bf     = qkv_bf;  // 8192x1536 bf16 over dead qkv+attnpre regions (contiguous)

  // weight prep (one launch)
  tc7_kernel<<<612, 256, 0, stream>>>(wqkv, wproj, wg1, wg2, wfc1, wfc2, wknn,
                                      wqkvT, wprojT, wg1T, wg2T, wfc1T, wfc2T, wcT);
  // LN1
  ln_kernel<<<2048, 256, 0, stream>>>(x, ln1g, ln1b, nx_bf);
  // qkv = nx @ w_qkv -> bf16 (Q pre-scaled, V^T scatter)
  gemm128_kernel<6><<<dim3(9, 64), 256, 0, stream>>>(nx_bf, nx_bf, 384, wqkvT, 1152, 384,
                                                     nullptr, nullptr, qkv_bf,
                                                     nullptr, nullptr, nullptr, Vt_b);
  // GBb = nx @ [W1 | W2-W1] -> bf16
  gemm128_kernel<0><<<dim3(6, 64), 256, 0, stream>>>(nx_bf, nx_bf, 384, wcT, 768, 384,
                                                     nullptr, nullptr, GBb,
                                                     nullptr, nullptr, nullptr, nullptr);
  // attention (no-barrier, key-split=2) + combine
  attn1_kernel<<<dim3(32, 24, 2), 256, 0, stream>>>(qkv_bf, Vt_b, OP, LS);
  attn2_kernel<<<3072, 256, 0, stream>>>(OP, LS, attnpre);
  // proj (+b_proj) -> bf16
  gemm128_kernel<2><<<dim3(3, 64), 256, 0, stream>>>(attnpre, attnpre, 384, wprojT, 384, 384,
                                                     bproj, nullptr, attn_bf,
                                                     nullptr, nullptr, nullptr, nullptr);
  // EdgeConv gather-max
  knn_kernel<<<2048, 256, 0, stream>>>(GBb, kidx, bknn, knn_bf);
  // gate hidden: gelu([attn|knn] @ w_g1 + b_g1) -> bf16
  gemm128_kernel<3><<<dim3(3, 64), 256, 0, stream>>>(attn_bf, knn_bf, 384, wg1T, 384, 768,
                                                     bg1, nullptr, t1_bf,
                                                     nullptr, nullptr, nullptr, nullptr);
  // gate + fuse + residual: x2 = x + (1-g)*attn + g*knn
  gemm128_kernel<4><<<dim3(3, 64), 256, 0, stream>>>(t1_bf, t1_bf, 384, wg2T, 384, 384,
                                                     bg2, x2, nullptr,
                                                     attn_bf, knn_bf, x, nullptr);
  // LN2
  ln_kernel<<<2048, 256, 0, stream>>>(x2, ln2g, ln2b, nx2_bf);
  // fc1: gelu(nx2 @ w_fc1 + b_fc1) -> bf16
  gemm128_kernel<3><<<dim3(12, 64), 256, 0, stream>>>(nx2_bf, nx2_bf, 384, wfc1T, 1536, 384,
                                                      bfc1, nullptr, h_bf,
                                                      nullptr, nullptr, nullptr, nullptr);
  // fc2: out = x2 + h @ w_fc2 + b_fc2
  gemm128_kernel<5><<<dim3(3, 64), 256, 0, stream>>>(h_bf, h_bf, 1536, wfc2T, 384, 1536,
                                                     bfc2, out, nullptr,
                                                     nullptr, nullptr, x2, nullptr);
  (void)in_sizes; (void)n_in; (void)out_size; (void)ws_size;
}

// Round 6
// 333.951 us; speedup vs baseline: 1.3224x; 1.3224x over previous
//
#include <hip/hip_runtime.h>
#include <math.h>

typedef unsigned short u16;
typedef __attribute__((ext_vector_type(8))) short short8;
typedef __attribute__((ext_vector_type(4))) float floatx4;
typedef __attribute__((ext_vector_type(4))) short sh4v;

union sh4u { sh4v v; u16 u[4]; };
union sh8u { short8 v; u16 u[8]; };

__device__ __forceinline__ floatx4 mfma16(short8 a, short8 b, floatx4 c) {
  return __builtin_amdgcn_mfma_f32_16x16x32_bf16(a, b, c, 0, 0, 0);
}

__device__ __forceinline__ floatx4 zero4() {
  floatx4 z = {0.f, 0.f, 0.f, 0.f};
  return z;
}

__device__ __forceinline__ u16 f2b(float f) {
  union { float f; unsigned u; } v; v.f = f;
  unsigned u = v.u;
  return (u16)((u + 0x7FFFu + ((u >> 16) & 1u)) >> 16);
}

__device__ __forceinline__ float b2f(u16 u) {
  union { unsigned u; float f; } v; v.u = ((unsigned)u) << 16;
  return v.f;
}

__device__ __forceinline__ float gelu_exact(float x) {
  return 0.5f * x * (1.f + erff(x * 0.70710678118654752440f));
}

__device__ __forceinline__ unsigned pack2(float a, float b) {
  return (unsigned)f2b(a) | ((unsigned)f2b(b) << 16);
}

// truncating pack of two f32 -> two bf16 in one v_perm
__device__ __forceinline__ unsigned permpack(float p0, float p1) {
  return __builtin_amdgcn_perm(__float_as_uint(p1), __float_as_uint(p0), 0x07060302u);
}

// ------------- weight prep: transpose-convert 6 weights + wcT build, one launch -------------
__global__ __launch_bounds__(256) void tc7_kernel(
    const float* __restrict__ p0, const float* __restrict__ p1,
    const float* __restrict__ p2, const float* __restrict__ p3,
    const float* __restrict__ p4, const float* __restrict__ p5,
    const float* __restrict__ wknn,
    u16* __restrict__ o0, u16* __restrict__ o1, u16* __restrict__ o2,
    u16* __restrict__ o3, u16* __restrict__ o4, u16* __restrict__ o5,
    u16* __restrict__ wcT) {
  __shared__ u16 L[64][66];
  int t = blockIdx.x, tid = threadIdx.x;
  if (t >= 540) {
    t -= 540;                       // 6 k-tiles x 12 j-tiles
    int tk = t / 12, tn = t % 12;
    int k0 = tk * 64, j0 = tn * 64;
#pragma unroll
    for (int i = 0; i < 4; i++) {
      int c = tid + 256 * i;
      int r = c >> 4, c4 = (c & 15) * 4;
      floatx4 v;
      if (j0 < 384) {
        v = *(const floatx4*)(wknn + (size_t)(k0 + r) * 384 + j0 + c4);
      } else {
        floatx4 a = *(const floatx4*)(wknn + (size_t)(384 + k0 + r) * 384 + (j0 - 384) + c4);
        floatx4 b = *(const floatx4*)(wknn + (size_t)(k0 + r) * 384 + (j0 - 384) + c4);
        v = a - b;
      }
      *(unsigned*)&L[r][c4]     = pack2(v[0], v[1]);
      *(unsigned*)&L[r][c4 + 2] = pack2(v[2], v[3]);
    }
    __syncthreads();
#pragma unroll
    for (int i = 0; i < 2; i++) {
      int c = tid + 256 * i;
      int nn = c >> 3, k8 = (c & 7) * 8;
      sh8u pk;
#pragma unroll
      for (int j = 0; j < 8; j++) pk.u[j] = L[k8 + j][nn];
      *(short8*)(wcT + (size_t)(j0 + nn) * 384 + k0 + k8) = pk.v;
    }
    return;
  }
  const float* src; u16* dst; int Kd, Nd, tk, tn;
  if      (t < 108) { src = p0; dst = o0; Kd = 384;  Nd = 1152; tk = t / 18; tn = t % 18; }
  else if (t < 144) { src = p1; dst = o1; Kd = 384;  Nd = 384;  t -= 108; tk = t / 6;  tn = t % 6; }
  else if (t < 216) { src = p2; dst = o2; Kd = 768;  Nd = 384;  t -= 144; tk = t / 6;  tn = t % 6; }
  else if (t < 252) { src = p3; dst = o3; Kd = 384;  Nd = 384;  t -= 216; tk = t / 6;  tn = t % 6; }
  else if (t < 396) { src = p4; dst = o4; Kd = 384;  Nd = 1536; t -= 252; tk = t / 24; tn = t % 24; }
  else              { src = p5; dst = o5; Kd = 1536; Nd = 384;  t -= 396; tk = t / 6;  tn = t % 6; }
  int k0 = tk * 64, n0 = tn * 64;
#pragma unroll
  for (int i = 0; i < 4; i++) {
    int c = tid + 256 * i;
    int r = c >> 4, c4 = (c & 15) * 4;
    floatx4 v = *(const floatx4*)(src + (size_t)(k0 + r) * Nd + n0 + c4);
    *(unsigned*)&L[r][c4]     = pack2(v[0], v[1]);
    *(unsigned*)&L[r][c4 + 2] = pack2(v[2], v[3]);
  }
  __syncthreads();
#pragma unroll
  for (int i = 0; i < 2; i++) {
    int c = tid + 256 * i;
    int nn = c >> 3, k8 = (c & 7) * 8;
    sh8u pk;
#pragma unroll
    for (int j = 0; j < 8; j++) pk.u[j] = L[k8 + j][nn];
    *(short8*)(dst + (size_t)(n0 + nn) * Kd + k0 + k8) = pk.v;
  }
}

// ---------------- LayerNorm (fp32 in -> bf16 out), one wave per row of 384 ----------------
__global__ __launch_bounds__(256) void ln_kernel(const float* __restrict__ x,
                                                 const float* __restrict__ g,
                                                 const float* __restrict__ bia,
                                                 u16* __restrict__ out) {
  int wave = threadIdx.x >> 6, lane = threadIdx.x & 63;
  int row = blockIdx.x * 4 + wave;
  const float* xr = x + (size_t)row * 384;
  float v[6];
  float s = 0.f;
#pragma unroll
  for (int j = 0; j < 6; j++) { v[j] = xr[lane + 64 * j]; s += v[j]; }
#pragma unroll
  for (int off = 32; off > 0; off >>= 1) s += __shfl_xor(s, off);
  float mu = s * (1.f / 384.f);
  float ss = 0.f;
#pragma unroll
  for (int j = 0; j < 6; j++) { float d = v[j] - mu; ss += d * d; }
#pragma unroll
  for (int off = 32; off > 0; off >>= 1) ss += __shfl_xor(ss, off);
  float rstd = rsqrtf(ss * (1.f / 384.f) + 1e-5f);
  u16* orow = out + (size_t)row * 384;
#pragma unroll
  for (int j = 0; j < 6; j++) {
    int d = lane + 64 * j;
    orow[d] = f2b((v[j] - mu) * rstd * g[d] + bia[d]);
  }
}

// ---------------- gemm128: 128x128 tile, BK=64, B pre-transposed, optional A concat ----------------
// EPI: 2 +bias -> bf16 | 3 gelu(+bias) -> bf16 | 4 gate -> f32 | 5 +bias+resid -> f32
//      8 fused qkv+GB: n0<1152 -> qkv (Q pre-scale, V^T scatter), else GBb bf16
template <int EPI>
__global__ __launch_bounds__(256) void gemm128_kernel(
    const u16* __restrict__ A0, const u16* __restrict__ A1, int Ksplit,
    const u16* __restrict__ BwT, const u16* __restrict__ BwT2, int N, int K,
    const float* __restrict__ bias,
    float* __restrict__ outF, u16* __restrict__ outB, u16* __restrict__ outB2,
    const u16* __restrict__ eA16, const u16* __restrict__ eK16,
    const float* __restrict__ eX, u16* __restrict__ outV) {
  __shared__ u16 As[128][72];
  __shared__ u16 Bs[128][72];
  int tid = threadIdx.x;
  int lane = tid & 63, wave = tid >> 6, quad = lane >> 4, l16 = lane & 15;
  int n0 = blockIdx.x * 128, m0 = blockIdx.y * 128;
  int wm = (wave >> 1) * 64, wn = (wave & 1) * 64;
  const u16* Bsrc = BwT;
  int nbase = n0;
  if (EPI == 8 && n0 >= 1152) { Bsrc = BwT2; nbase = n0 - 1152; }
  floatx4 acc[4][4];
#pragma unroll
  for (int i = 0; i < 4; i++)
#pragma unroll
    for (int j = 0; j < 4; j++) acc[i][j] = zero4();

  for (int k0 = 0; k0 < K; k0 += 64) {
    const u16* Ap;
    int kk, sA;
    if (k0 < Ksplit) { Ap = A0; kk = k0; sA = Ksplit; }
    else             { Ap = A1; kk = k0 - Ksplit; sA = K - Ksplit; }
#pragma unroll
    for (int i = 0; i < 4; i++) {
      int c = tid + 256 * i;
      int row = c >> 3, c8 = (c & 7) * 8;
      *(short8*)&As[row][c8] =
          *(const short8*)(Ap + (size_t)(m0 + row) * sA + kk + c8);
      *(short8*)&Bs[row][c8] =
          *(const short8*)(Bsrc + (size_t)(nbase + row) * K + k0 + c8);
    }
    __syncthreads();
#pragma unroll
    for (int kh = 0; kh < 2; kh++) {
      short8 af[4], bfr[4];
#pragma unroll
      for (int ti = 0; ti < 4; ti++)
        af[ti] = *(const short8*)&As[wm + ti * 16 + l16][kh * 32 + quad * 8];
#pragma unroll
      for (int tj = 0; tj < 4; tj++)
        bfr[tj] = *(const short8*)&Bs[wn + tj * 16 + l16][kh * 32 + quad * 8];
#pragma unroll
      for (int ti = 0; ti < 4; ti++)
#pragma unroll
        for (int tj = 0; tj < 4; tj++)
          acc[ti][tj] = mfma16(af[ti], bfr[tj], acc[ti][tj]);
    }
    __syncthreads();
  }

#pragma unroll
  for (int ti = 0; ti < 4; ti++)
#pragma unroll
    for (int tj = 0; tj < 4; tj++) {
      int col = n0 + wn + tj * 16 + l16;
      int row0 = m0 + wm + ti * 16 + quad * 4;
      if (EPI == 8) {
        if (n0 < 1152) {
          float sc = (col < 384) ? 0.18033688011112042f : 1.f;  // Q * 0.125*log2(e)
          sh4u pk;
#pragma unroll
          for (int r = 0; r < 4; r++) {
            u16 bv = f2b(acc[ti][tj][r] * sc);
            outB[(size_t)(row0 + r) * 1152 + col] = bv;
            pk.u[r] = bv;
          }
          if (col >= 768) {
            int b = row0 >> 11, n = row0 & 2047;
            int hd = col - 768;
            *(sh4v*)(outV + ((size_t)(b * 6 + (hd >> 6)) * 64 + (hd & 63)) * 2048 + n) = pk.v;
          }
        } else {
#pragma unroll
          for (int r = 0; r < 4; r++)
            outB2[(size_t)(row0 + r) * 768 + (col - 1152)] = f2b(acc[ti][tj][r]);
        }
      } else {
#pragma unroll
        for (int r = 0; r < 4; r++) {
          size_t rc = (size_t)(row0 + r) * N + col;
          float v = acc[ti][tj][r];
          if (EPI == 2) {
            outB[rc] = f2b(v + bias[col]);
          } else if (EPI == 3) {
            outB[rc] = f2b(gelu_exact(v + bias[col]));
          } else if (EPI == 4) {
            float gte = 1.f / (1.f + __expf(-(v + bias[col])));
            float fu = (1.f - gte) * b2f(eA16[rc]) + gte * b2f(eK16[rc]);
            outF[rc] = eX[rc] + fu;
          } else if (EPI == 5) {
            outF[rc] = v + bias[col] + eX[rc];
          }
        }
      }
    }
}

// ---------------- attention: 2-wave blocks, 32 q-rows/wave, LDS-staged, fused norm ----------------
// grid (32 qblocks, 24 bh), 128 thr. Q pre-scaled by 0.125*log2e -> p = exp2(s).
// S^T = K.Q^T; P via per-wave LDS; O^T = V^T.P^T. Reg-prefetch staging, 1 LDS buffer.
__global__ __launch_bounds__(128) void attn1_kernel(const u16* __restrict__ qkv,
                                                    const u16* __restrict__ Vt,
                                                    u16* __restrict__ attnpre) {
  __shared__ u16 Ks[64][72];    // K tile [key][dim]
  __shared__ u16 Vts[64][72];   // V^T tile [dim][key]
  __shared__ u16 Ps[2][32][72]; // per-wave P [qrow(32)][key]
  int tid = threadIdx.x;
  int lane = tid & 63, w = tid >> 6, quad = lane >> 4, l16 = lane & 15;
  int bh = blockIdx.y, b = bh / 6, h = bh % 6;
  int q0 = blockIdx.x * 64;
  const u16* qbase = qkv + (size_t)b * 2048 * 1152 + h * 64;
  const u16* kbase = qbase + 384;
  const u16* vtb = Vt + (size_t)bh * 64 * 2048;
  // Q frags: wave w covers q-rows q0 + w*32 + s*16 + l16, s in {0,1}
  short8 qf[2][2];
#pragma unroll
  for (int s = 0; s < 2; s++) {
    int qrow = q0 + w * 32 + s * 16 + l16;
    qf[s][0] = *(const short8*)(qbase + (size_t)qrow * 1152 + quad * 8);
    qf[s][1] = *(const short8*)(qbase + (size_t)qrow * 1152 + 32 + quad * 8);
  }
  floatx4 O[4][2];
  float lsum[2] = {0.f, 0.f};
#pragma unroll
  for (int i = 0; i < 4; i++)
#pragma unroll
    for (int s = 0; s < 2; s++) O[i][s] = zero4();

  // staging: 512 chunks of 8 bf16; thread handles rows rb+16i, col c8
  int rb = tid >> 3, c8 = (tid & 7) * 8;
  short8 rk[4], rv[4];
#pragma unroll
  for (int i = 0; i < 4; i++) {
    rk[i] = *(const short8*)(kbase + (size_t)(rb + 16 * i) * 1152 + c8);
    rv[i] = *(const short8*)(vtb + (size_t)(rb + 16 * i) * 2048 + c8);
  }

  for (int kt = 0; kt < 32; kt++) {
    __syncthreads();  // previous tile's frag reads done
#pragma unroll
    for (int i = 0; i < 4; i++) {
      *(short8*)&Ks[rb + 16 * i][c8] = rk[i];
      *(short8*)&Vts[rb + 16 * i][c8] = rv[i];
    }
    __syncthreads();
    if (kt < 31) {
      int key0 = (kt + 1) * 64;
#pragma unroll
      for (int i = 0; i < 4; i++) {
        rk[i] = *(const short8*)(kbase + (size_t)(key0 + rb + 16 * i) * 1152 + c8);
        rv[i] = *(const short8*)(vtb + (size_t)(rb + 16 * i) * 2048 + key0 + c8);
      }
    }
    // S^T: st[mt][s] = S^T[key=mt*16+quad*4+r][q = s*16+l16]
#pragma unroll
    for (int mt = 0; mt < 4; mt++) {
      short8 k0 = *(const short8*)&Ks[mt * 16 + l16][quad * 8];
      short8 k1 = *(const short8*)&Ks[mt * 16 + l16][32 + quad * 8];
#pragma unroll
      for (int s = 0; s < 2; s++) {
        floatx4 st = mfma16(k0, qf[s][0], zero4());
        st = mfma16(k1, qf[s][1], st);
        float p0 = exp2f(st[0]), p1 = exp2f(st[1]);
        float p2 = exp2f(st[2]), p3 = exp2f(st[3]);
        lsum[s] += (p0 + p1) + (p2 + p3);
        uint2 pk;
        pk.x = permpack(p0, p1);
        pk.y = permpack(p2, p3);
        *(uint2*)&Ps[w][s * 16 + l16][mt * 16 + quad * 4] = pk;
      }
    }
    // PV: O[mt2][s] += V^T frags x P^T frags (intra-wave Ps, no barrier)
    short8 pf[2][2];
#pragma unroll
    for (int s = 0; s < 2; s++) {
      pf[s][0] = *(const short8*)&Ps[w][s * 16 + l16][quad * 8];
      pf[s][1] = *(const short8*)&Ps[w][s * 16 + l16][32 + quad * 8];
    }
#pragma unroll
    for (int mt2 = 0; mt2 < 4; mt2++) {
      short8 v0 = *(const short8*)&Vts[mt2 * 16 + l16][quad * 8];
      short8 v1 = *(const short8*)&Vts[mt2 * 16 + l16][32 + quad * 8];
#pragma unroll
      for (int s = 0; s < 2; s++) {
        O[mt2][s] = mfma16(v0, pf[s][0], O[mt2][s]);
        O[mt2][s] = mfma16(v1, pf[s][1], O[mt2][s]);
      }
    }
  }
  // reduce lsum across quads (lane bits 4,5), normalize, store
#pragma unroll
  for (int s = 0; s < 2; s++) {
    lsum[s] += __shfl_xor(lsum[s], 16);
    lsum[s] += __shfl_xor(lsum[s], 32);
    float rl = 1.f / lsum[s];
    u16* orow = attnpre + (size_t)(b * 2048 + q0 + w * 32 + s * 16 + l16) * 384 + h * 64;
#pragma unroll
    for (int mt2 = 0; mt2 < 4; mt2++) {
      sh4u pk;
#pragma unroll
      for (int r = 0; r < 4; r++) pk.u[r] = f2b(O[mt2][s][r] * rl);
      *(sh4v*)(orow + mt2 * 16 + quad * 4) = pk.v;
    }
  }
}

// ---------------- EdgeConv gather (bf16 G|base) + leaky-relu + max over K=8 ----------------
__global__ __launch_bounds__(256) void knn_kernel(const u16* __restrict__ GBb,
                                                  const int* __restrict__ idx,
                                                  const float* __restrict__ bknn,
                                                  u16* __restrict__ outB) {
  int wave = threadIdx.x >> 6, lane = threadIdx.x & 63;
  int row = blockIdx.x * 4 + wave;  // 0..8191
  int b = row >> 11, n = row & 2047;
  float base[6], acc[6];
#pragma unroll
  for (int j = 0; j < 6; j++) {
    int d = lane + 64 * j;
    base[j] = b2f(GBb[(size_t)row * 768 + 384 + d]) + bknn[d];
    acc[j] = -1e30f;
  }
  for (int kk = 0; kk < 8; kk++) {
    int g = idx[(b * 8 + kk) * 2048 + n];
    const u16* Gr = GBb + (size_t)g * 768;
#pragma unroll
    for (int j = 0; j < 6; j++) {
      float v = b2f(Gr[lane + 64 * j]) + base[j];
      v = v > 0.f ? v : 0.2f * v;
      acc[j] = fmaxf(acc[j], v);
    }
  }
#pragma unroll
  for (int j = 0; j < 6; j++)
    outB[(size_t)row * 384 + lane + 64 * j] = f2b(acc[j]);
}

// ---------------- launch ----------------
extern "C" void kernel_launch(void* const* d_in, const int* in_sizes, int n_in,
                              void* d_out, int out_size, void* d_ws, size_t ws_size,
                              hipStream_t stream) {
  const float* x    = (const float*)d_in[0];
  const int* kidx   = (const int*)d_in[1];
  const float* ln1g = (const float*)d_in[2];
  const float* ln1b = (const float*)d_in[3];
  const float* wqkv = (const float*)d_in[4];
  const float* wproj= (const float*)d_in[5];
  const float* bproj= (const float*)d_in[6];
  const float* wknn = (const float*)d_in[7];
  const float* bknn = (const float*)d_in[8];
  const float* wg1  = (const float*)d_in[9];
  const float* bg1  = (const float*)d_in[10];
  const float* wg2  = (const float*)d_in[11];
  const float* bg2  = (const float*)d_in[12];
  const float* ln2g = (const float*)d_in[13];
  const float* ln2b = (const float*)d_in[14];
  const float* wfc1 = (const float*)d_in[15];
  const float* bfc1 = (const float*)d_in[16];
  const float* wfc2 = (const float*)d_in[17];
  const float* bfc2 = (const float*)d_in[18];
  float* out = (float*)d_out;

  const int M = 8192;
  char* ws = (char*)d_ws;
  size_t off = 0;
  auto alloc = [&](size_t bytes) -> char* {
    char* p = ws + off;
    off += (bytes + 255) & ~(size_t)255;
    return p;
  };
  u16* nx_bf    = (u16*)alloc((size_t)M * 384 * 2);
  u16* qkv_bf   = (u16*)alloc((size_t)M * 1152 * 2);   // + attnpre reused as h_bf
  u16* attnpre  = (u16*)alloc((size_t)M * 384 * 2);
  u16* attn_bf  = (u16*)alloc((size_t)M * 384 * 2);
  u16* GBb      = (u16*)alloc((size_t)M * 768 * 2);    // [G | base] bf16
  u16* knn_bf   = (u16*)alloc((size_t)M * 384 * 2);
  float* x2     = (float*)alloc((size_t)M * 384 * 4);
  u16* t1_bf    = (u16*)alloc((size_t)M * 384 * 2);
  u16* nx2_bf   = (u16*)alloc((size_t)M * 384 * 2);
  u16* Vt_b     = (u16*)alloc((size_t)24 * 64 * 2048 * 2);
  u16* wqkvT    = (u16*)alloc((size_t)1152 * 384 * 2);
  u16* wprojT   = (u16*)alloc(384 * 384 * 2);
  u16* wcT      = (u16*)alloc((size_t)768 * 384 * 2);
  u16* wg1T     = (u16*)alloc((size_t)384 * 768 * 2);
  u16* wg2T     = (u16*)alloc(384 * 384 * 2);
  u16* wfc1T    = (u16*)alloc((size_t)1536 * 384 * 2);
  u16* wfc2T    = (u16*)alloc((size_t)384 * 1536 * 2);
  u16* h_bf     = qkv_bf;  // 8192x1536 bf16 over dead qkv+attnpre regions (contiguous)

  // weight prep (one launch)
  tc7_kernel<<<612, 256, 0, stream>>>(wqkv, wproj, wg1, wg2, wfc1, wfc2, wknn,
                                      wqkvT, wprojT, wg1T, wg2T, wfc1T, wfc2T, wcT);
  // LN1
  ln_kernel<<<2048, 256, 0, stream>>>(x, ln1g, ln1b, nx_bf);
  // fused qkv + GB: [qkv | GBb] = nx @ [wqkvT | wcT]  (960 blocks)
  gemm128_kernel<8><<<dim3(15, 64), 256, 0, stream>>>(nx_bf, nx_bf, 384, wqkvT, wcT, 1920, 384,
                                                      nullptr, nullptr, qkv_bf, GBb,
                                                      nullptr, nullptr, nullptr, Vt_b);
  // attention (fused normalize)
  attn1_kernel<<<dim3(32, 24), 128, 0, stream>>>(qkv_bf, Vt_b, attnpre);
  // proj (+b_proj) -> bf16
  gemm128_kernel<2><<<dim3(3, 64), 256, 0, stream>>>(attnpre, attnpre, 384, wprojT, nullptr, 384, 384,
                                                     bproj, nullptr, attn_bf, nullptr,
                                                     nullptr, nullptr, nullptr, nullptr);
  // EdgeConv gather-max
  knn_kernel<<<2048, 256, 0, stream>>>(GBb, kidx, bknn, knn_bf);
  // gate hidden: gelu([attn|knn] @ w_g1 + b_g1) -> bf16
  gemm128_kernel<3><<<dim3(3, 64), 256, 0, stream>>>(attn_bf, knn_bf, 384, wg1T, nullptr, 384, 768,
                                                     bg1, nullptr, t1_bf, nullptr,
                                                     nullptr, nullptr, nullptr, nullptr);
  // gate + fuse + residual: x2 = x + (1-g)*attn + g*knn
  gemm128_kernel<4><<<dim3(3, 64), 256, 0, stream>>>(t1_bf, t1_bf, 384, wg2T, nullptr, 384, 384,
                                                     bg2, x2, nullptr, nullptr,
                                                     attn_bf, knn_bf, x, nullptr);
  // LN2
  ln_kernel<<<2048, 256, 0, stream>>>(x2, ln2g, ln2b, nx2_bf);
  // fc1: gelu(nx2 @ w_fc1 + b_fc1) -> bf16
  gemm128_kernel<3><<<dim3(12, 64), 256, 0, stream>>>(nx2_bf, nx2_bf, 384, wfc1T, nullptr, 1536, 384,
                                                      bfc1, nullptr, h_bf, nullptr,
                                                      nullptr, nullptr, nullptr, nullptr);
  // fc2: out = x2 + h @ w_fc2 + b_fc2
  gemm128_kernel<5><<<dim3(3, 64), 256, 0, stream>>>(h_bf, h_bf, 1536, wfc2T, nullptr, 384, 1536,
                                                     bfc2, out, nullptr, nullptr,
                                                     nullptr, nullptr, x2, nullptr);
  (void)in_sizes; (void)n_in; (void)out_size; (void)ws_size;
}

// Round 7
// 314.422 us; speedup vs baseline: 1.4046x; 1.0621x over previous
//
#include <hip/hip_runtime.h>
#include <math.h>

typedef unsigned short u16;
typedef __attribute__((ext_vector_type(8))) short short8;
typedef __attribute__((ext_vector_type(4))) float floatx4;
typedef __attribute__((ext_vector_type(4))) short sh4v;

union sh4u { sh4v v; u16 u[4]; };
union sh8u { short8 v; u16 u[8]; };

__device__ __forceinline__ floatx4 mfma16(short8 a, short8 b, floatx4 c) {
  return __builtin_amdgcn_mfma_f32_16x16x32_bf16(a, b, c, 0, 0, 0);
}

__device__ __forceinline__ floatx4 zero4() {
  floatx4 z = {0.f, 0.f, 0.f, 0.f};
  return z;
}

__device__ __forceinline__ u16 f2b(float f) {
  union { float f; unsigned u; } v; v.f = f;
  unsigned u = v.u;
  return (u16)((u + 0x7FFFu + ((u >> 16) & 1u)) >> 16);
}

__device__ __forceinline__ float b2f(u16 u) {
  union { unsigned u; float f; } v; v.u = ((unsigned)u) << 16;
  return v.f;
}

__device__ __forceinline__ float gelu_exact(float x) {
  return 0.5f * x * (1.f + erff(x * 0.70710678118654752440f));
}

__device__ __forceinline__ unsigned pack2(float a, float b) {
  return (unsigned)f2b(a) | ((unsigned)f2b(b) << 16);
}

// truncating pack of two f32 -> two bf16 in one v_perm
__device__ __forceinline__ unsigned permpack(float p0, float p1) {
  return __builtin_amdgcn_perm(__float_as_uint(p1), __float_as_uint(p0), 0x07060302u);
}

// ------------- fat kernel: weight transpose-convert (blocks 0..611) + LN1 (612..2659) -------------
__global__ __launch_bounds__(256) void tcln_kernel(
    const float* __restrict__ p0, const float* __restrict__ p1,
    const float* __restrict__ p2, const float* __restrict__ p3,
    const float* __restrict__ p4, const float* __restrict__ p5,
    const float* __restrict__ wknn,
    u16* __restrict__ o0, u16* __restrict__ o1, u16* __restrict__ o2,
    u16* __restrict__ o3, u16* __restrict__ o4, u16* __restrict__ o5,
    u16* __restrict__ wcT,
    const float* __restrict__ x, const float* __restrict__ g,
    const float* __restrict__ bia, u16* __restrict__ nx) {
  __shared__ u16 L[64][66];
  int t = blockIdx.x, tid = threadIdx.x;
  if (t >= 612) {
    // ---- LN1: one wave per row ----
    int wave = tid >> 6, lane = tid & 63;
    int row = (t - 612) * 4 + wave;
    const float* xr = x + (size_t)row * 384;
    float v[6];
    float s = 0.f;
#pragma unroll
    for (int j = 0; j < 6; j++) { v[j] = xr[lane + 64 * j]; s += v[j]; }
#pragma unroll
    for (int off = 32; off > 0; off >>= 1) s += __shfl_xor(s, off);
    float mu = s * (1.f / 384.f);
    float ss = 0.f;
#pragma unroll
    for (int j = 0; j < 6; j++) { float d = v[j] - mu; ss += d * d; }
#pragma unroll
    for (int off = 32; off > 0; off >>= 1) ss += __shfl_xor(ss, off);
    float rstd = rsqrtf(ss * (1.f / 384.f) + 1e-5f);
    u16* orow = nx + (size_t)row * 384;
#pragma unroll
    for (int j = 0; j < 6; j++) {
      int d = lane + 64 * j;
      orow[d] = f2b((v[j] - mu) * rstd * g[d] + bia[d]);
    }
    return;
  }
  if (t >= 540) {
    t -= 540;                       // wcT: 6 k-tiles x 12 j-tiles
    int tk = t / 12, tn = t % 12;
    int k0 = tk * 64, j0 = tn * 64;
#pragma unroll
    for (int i = 0; i < 4; i++) {
      int c = tid + 256 * i;
      int r = c >> 4, c4 = (c & 15) * 4;
      floatx4 v;
      if (j0 < 384) {
        v = *(const floatx4*)(wknn + (size_t)(k0 + r) * 384 + j0 + c4);
      } else {
        floatx4 a = *(const floatx4*)(wknn + (size_t)(384 + k0 + r) * 384 + (j0 - 384) + c4);
        floatx4 b = *(const floatx4*)(wknn + (size_t)(k0 + r) * 384 + (j0 - 384) + c4);
        v = a - b;
      }
      *(unsigned*)&L[r][c4]     = pack2(v[0], v[1]);
      *(unsigned*)&L[r][c4 + 2] = pack2(v[2], v[3]);
    }
    __syncthreads();
#pragma unroll
    for (int i = 0; i < 2; i++) {
      int c = tid + 256 * i;
      int nn = c >> 3, k8 = (c & 7) * 8;
      sh8u pk;
#pragma unroll
      for (int j = 0; j < 8; j++) pk.u[j] = L[k8 + j][nn];
      *(short8*)(wcT + (size_t)(j0 + nn) * 384 + k0 + k8) = pk.v;
    }
    return;
  }
  const float* src; u16* dst; int Kd, Nd, tk, tn;
  if      (t < 108) { src = p0; dst = o0; Kd = 384;  Nd = 1152; tk = t / 18; tn = t % 18; }
  else if (t < 144) { src = p1; dst = o1; Kd = 384;  Nd = 384;  t -= 108; tk = t / 6;  tn = t % 6; }
  else if (t < 216) { src = p2; dst = o2; Kd = 768;  Nd = 384;  t -= 144; tk = t / 6;  tn = t % 6; }
  else if (t < 252) { src = p3; dst = o3; Kd = 384;  Nd = 384;  t -= 216; tk = t / 6;  tn = t % 6; }
  else if (t < 396) { src = p4; dst = o4; Kd = 384;  Nd = 1536; t -= 252; tk = t / 24; tn = t % 24; }
  else              { src = p5; dst = o5; Kd = 1536; Nd = 384;  t -= 396; tk = t / 6;  tn = t % 6; }
  int k0 = tk * 64, n0 = tn * 64;
#pragma unroll
  for (int i = 0; i < 4; i++) {
    int c = tid + 256 * i;
    int r = c >> 4, c4 = (c & 15) * 4;
    floatx4 v = *(const floatx4*)(src + (size_t)(k0 + r) * Nd + n0 + c4);
    *(unsigned*)&L[r][c4]     = pack2(v[0], v[1]);
    *(unsigned*)&L[r][c4 + 2] = pack2(v[2], v[3]);
  }
  __syncthreads();
#pragma unroll
  for (int i = 0; i < 2; i++) {
    int c = tid + 256 * i;
    int nn = c >> 3, k8 = (c & 7) * 8;
    sh8u pk;
#pragma unroll
    for (int j = 0; j < 8; j++) pk.u[j] = L[k8 + j][nn];
    *(short8*)(dst + (size_t)(n0 + nn) * Kd + k0 + k8) = pk.v;
  }
}

// ---------------- LayerNorm (fp32 in -> bf16 out), one wave per row of 384 ----------------
__global__ __launch_bounds__(256) void ln_kernel(const float* __restrict__ x,
                                                 const float* __restrict__ g,
                                                 const float* __restrict__ bia,
                                                 u16* __restrict__ out) {
  int wave = threadIdx.x >> 6, lane = threadIdx.x & 63;
  int row = blockIdx.x * 4 + wave;
  const float* xr = x + (size_t)row * 384;
  float v[6];
  float s = 0.f;
#pragma unroll
  for (int j = 0; j < 6; j++) { v[j] = xr[lane + 64 * j]; s += v[j]; }
#pragma unroll
  for (int off = 32; off > 0; off >>= 1) s += __shfl_xor(s, off);
  float mu = s * (1.f / 384.f);
  float ss = 0.f;
#pragma unroll
  for (int j = 0; j < 6; j++) { float d = v[j] - mu; ss += d * d; }
#pragma unroll
  for (int off = 32; off > 0; off >>= 1) ss += __shfl_xor(ss, off);
  float rstd = rsqrtf(ss * (1.f / 384.f) + 1e-5f);
  u16* orow = out + (size_t)row * 384;
#pragma unroll
  for (int j = 0; j < 6; j++) {
    int d = lane + 64 * j;
    orow[d] = f2b((v[j] - mu) * rstd * g[d] + bia[d]);
  }
}

// ---------------- gemm128: 128x128 tile, BK=64, B pre-transposed, optional A concat ----------------
// EPI: 3 gelu(+bias) -> bf16 | 4 gate -> f32 | 5 +bias+resid -> f32
//      8 fused qkv+GB: n0<1152 -> qkv (Q pre-scale, V^T scatter), else GBb bf16
template <int EPI>
__global__ __launch_bounds__(256) void gemm128_kernel(
    const u16* __restrict__ A0, const u16* __restrict__ A1, int Ksplit,
    const u16* __restrict__ BwT, const u16* __restrict__ BwT2, int N, int K,
    const float* __restrict__ bias,
    float* __restrict__ outF, u16* __restrict__ outB, u16* __restrict__ outB2,
    const u16* __restrict__ eA16, const u16* __restrict__ eK16,
    const float* __restrict__ eX, u16* __restrict__ outV) {
  __shared__ u16 As[128][72];
  __shared__ u16 Bs[128][72];
  int tid = threadIdx.x;
  int lane = tid & 63, wave = tid >> 6, quad = lane >> 4, l16 = lane & 15;
  int n0 = blockIdx.x * 128, m0 = blockIdx.y * 128;
  int wm = (wave >> 1) * 64, wn = (wave & 1) * 64;
  const u16* Bsrc = BwT;
  int nbase = n0;
  if (EPI == 8 && n0 >= 1152) { Bsrc = BwT2; nbase = n0 - 1152; }
  floatx4 acc[4][4];
#pragma unroll
  for (int i = 0; i < 4; i++)
#pragma unroll
    for (int j = 0; j < 4; j++) acc[i][j] = zero4();

  for (int k0 = 0; k0 < K; k0 += 64) {
    const u16* Ap;
    int kk, sA;
    if (k0 < Ksplit) { Ap = A0; kk = k0; sA = Ksplit; }
    else             { Ap = A1; kk = k0 - Ksplit; sA = K - Ksplit; }
#pragma unroll
    for (int i = 0; i < 4; i++) {
      int c = tid + 256 * i;
      int row = c >> 3, c8 = (c & 7) * 8;
      *(short8*)&As[row][c8] =
          *(const short8*)(Ap + (size_t)(m0 + row) * sA + kk + c8);
      *(short8*)&Bs[row][c8] =
          *(const short8*)(Bsrc + (size_t)(nbase + row) * K + k0 + c8);
    }
    __syncthreads();
#pragma unroll
    for (int kh = 0; kh < 2; kh++) {
      short8 af[4], bfr[4];
#pragma unroll
      for (int ti = 0; ti < 4; ti++)
        af[ti] = *(const short8*)&As[wm + ti * 16 + l16][kh * 32 + quad * 8];
#pragma unroll
      for (int tj = 0; tj < 4; tj++)
        bfr[tj] = *(const short8*)&Bs[wn + tj * 16 + l16][kh * 32 + quad * 8];
#pragma unroll
      for (int ti = 0; ti < 4; ti++)
#pragma unroll
        for (int tj = 0; tj < 4; tj++)
          acc[ti][tj] = mfma16(af[ti], bfr[tj], acc[ti][tj]);
    }
    __syncthreads();
  }

#pragma unroll
  for (int ti = 0; ti < 4; ti++)
#pragma unroll
    for (int tj = 0; tj < 4; tj++) {
      int col = n0 + wn + tj * 16 + l16;
      int row0 = m0 + wm + ti * 16 + quad * 4;
      if (EPI == 8) {
        if (n0 < 1152) {
          float sc = (col < 384) ? 0.18033688011112042f : 1.f;  // Q * 0.125*log2(e)
          sh4u pk;
#pragma unroll
          for (int r = 0; r < 4; r++) {
            u16 bv = f2b(acc[ti][tj][r] * sc);
            outB[(size_t)(row0 + r) * 1152 + col] = bv;
            pk.u[r] = bv;
          }
          if (col >= 768) {
            int b = row0 >> 11, n = row0 & 2047;
            int hd = col - 768;
            *(sh4v*)(outV + ((size_t)(b * 6 + (hd >> 6)) * 64 + (hd & 63)) * 2048 + n) = pk.v;
          }
        } else {
#pragma unroll
          for (int r = 0; r < 4; r++)
            outB2[(size_t)(row0 + r) * 768 + (col - 1152)] = f2b(acc[ti][tj][r]);
        }
      } else {
#pragma unroll
        for (int r = 0; r < 4; r++) {
          size_t rc = (size_t)(row0 + r) * N + col;
          float v = acc[ti][tj][r];
          if (EPI == 3) {
            outB[rc] = f2b(gelu_exact(v + bias[col]));
          } else if (EPI == 4) {
            float gte = 1.f / (1.f + __expf(-(v + bias[col])));
            float fu = (1.f - gte) * b2f(eA16[rc]) + gte * b2f(eK16[rc]);
            outF[rc] = eX[rc] + fu;
          } else if (EPI == 5) {
            outF[rc] = v + bias[col] + eX[rc];
          }
        }
      }
    }
}

// ---------------- attention: 4 waves x 32 q-rows, key-split=2, bf16 partials ----------------
// grid (16 qtiles of 128, 24 bh, 2 splits), 256 thr. Q pre-scaled by 0.125*log2e.
// S^T = K.Q^T; P via per-wave LDS; O^T = V^T.P^T. Reg-prefetch staging, 1 LDS buffer.
__global__ __launch_bounds__(256) void attn1_kernel(const u16* __restrict__ qkv,
                                                    const u16* __restrict__ Vt,
                                                    u16* __restrict__ OPb,
                                                    float* __restrict__ LS) {
  __shared__ u16 Ks[64][72];    // K tile [key][dim]
  __shared__ u16 Vts[64][72];   // V^T tile [dim][key]
  __shared__ u16 Ps[4][32][72]; // per-wave P [qrow(32)][key]
  int tid = threadIdx.x;
  int lane = tid & 63, w = tid >> 6, quad = lane >> 4, l16 = lane & 15;
  int bh = blockIdx.y, b = bh / 6, h = bh % 6;
  int q0 = blockIdx.x * 128, split = blockIdx.z;
  const u16* qbase = qkv + (size_t)b * 2048 * 1152 + h * 64;
  const u16* kbase = qbase + 384 + (size_t)split * 1024 * 1152;
  const u16* vtb = Vt + (size_t)bh * 64 * 2048 + split * 1024;
  // Q frags: wave w covers q-rows q0 + w*32 + s*16 + l16, s in {0,1}
  short8 qf[2][2];
#pragma unroll
  for (int s = 0; s < 2; s++) {
    int qrow = q0 + w * 32 + s * 16 + l16;
    qf[s][0] = *(const short8*)(qbase + (size_t)qrow * 1152 + quad * 8);
    qf[s][1] = *(const short8*)(qbase + (size_t)qrow * 1152 + 32 + quad * 8);
  }
  floatx4 O[4][2];
  float lsum[2] = {0.f, 0.f};
#pragma unroll
  for (int i = 0; i < 4; i++)
#pragma unroll
    for (int s = 0; s < 2; s++) O[i][s] = zero4();

  // staging: 512 chunks of 8 bf16 over 256 threads -> rows rb, rb+32
  int rb = tid >> 3, c8 = (tid & 7) * 8;
  short8 rk[2], rv[2];
  rk[0] = *(const short8*)(kbase + (size_t)rb * 1152 + c8);
  rk[1] = *(const short8*)(kbase + (size_t)(rb + 32) * 1152 + c8);
  rv[0] = *(const short8*)(vtb + (size_t)rb * 2048 + c8);
  rv[1] = *(const short8*)(vtb + (size_t)(rb + 32) * 2048 + c8);

  for (int kt = 0; kt < 16; kt++) {
    __syncthreads();  // previous tile's frag reads done
    *(short8*)&Ks[rb][c8] = rk[0];
    *(short8*)&Ks[rb + 32][c8] = rk[1];
    *(short8*)&Vts[rb][c8] = rv[0];
    *(short8*)&Vts[rb + 32][c8] = rv[1];
    __syncthreads();
    if (kt < 15) {
      int key0 = (kt + 1) * 64;
      rk[0] = *(const short8*)(kbase + (size_t)(key0 + rb) * 1152 + c8);
      rk[1] = *(const short8*)(kbase + (size_t)(key0 + rb + 32) * 1152 + c8);
      rv[0] = *(const short8*)(vtb + (size_t)rb * 2048 + key0 + c8);
      rv[1] = *(const short8*)(vtb + (size_t)(rb + 32) * 2048 + key0 + c8);
    }
    // S^T: st = S^T[key=mt*16+quad*4+r][q = s*16+l16]
#pragma unroll
    for (int mt = 0; mt < 4; mt++) {
      short8 k0 = *(const short8*)&Ks[mt * 16 + l16][quad * 8];
      short8 k1 = *(const short8*)&Ks[mt * 16 + l16][32 + quad * 8];
#pragma unroll
      for (int s = 0; s < 2; s++) {
        floatx4 st = mfma16(k0, qf[s][0], zero4());
        st = mfma16(k1, qf[s][1], st);
        float p0 = exp2f(st[0]), p1 = exp2f(st[1]);
        float p2 = exp2f(st[2]), p3 = exp2f(st[3]);
        lsum[s] += (p0 + p1) + (p2 + p3);
        uint2 pk;
        pk.x = permpack(p0, p1);
        pk.y = permpack(p2, p3);
        *(uint2*)&Ps[w][s * 16 + l16][mt * 16 + quad * 4] = pk;
      }
    }
    // PV (intra-wave Ps, no barrier)
    short8 pf[2][2];
#pragma unroll
    for (int s = 0; s < 2; s++) {
      pf[s][0] = *(const short8*)&Ps[w][s * 16 + l16][quad * 8];
      pf[s][1] = *(const short8*)&Ps[w][s * 16 + l16][32 + quad * 8];
    }
#pragma unroll
    for (int mt2 = 0; mt2 < 4; mt2++) {
      short8 v0 = *(const short8*)&Vts[mt2 * 16 + l16][quad * 8];
      short8 v1 = *(const short8*)&Vts[mt2 * 16 + l16][32 + quad * 8];
#pragma unroll
      for (int s = 0; s < 2; s++) {
        O[mt2][s] = mfma16(v0, pf[s][0], O[mt2][s]);
        O[mt2][s] = mfma16(v1, pf[s][1], O[mt2][s]);
      }
    }
  }
  // per-split epilogue: unnormalized bf16 partials + f32 row-sum
#pragma unroll
  for (int s = 0; s < 2; s++) {
    lsum[s] += __shfl_xor(lsum[s], 16);
    lsum[s] += __shfl_xor(lsum[s], 32);
    int row = b * 2048 + q0 + w * 32 + s * 16 + l16;
    u16* orow = OPb + (size_t)split * 8192 * 384 + (size_t)row * 384 + h * 64;
#pragma unroll
    for (int mt2 = 0; mt2 < 4; mt2++) {
      sh4u pk;
#pragma unroll
      for (int r = 0; r < 4; r++) pk.u[r] = f2b(O[mt2][s][r]);
      *(sh4v*)(orow + mt2 * 16 + quad * 4) = pk.v;
    }
    if (quad == 0) LS[split * 8192 + row] = lsum[s];
  }
}

// ---------------- fat kernel: proj GEMM w/ fused split-combine (blocks 0..191) + knn (192..2239) ----
__global__ __launch_bounds__(256) void projknn_kernel(
    const u16* __restrict__ OPb, const float* __restrict__ LS,
    const u16* __restrict__ BwT, const float* __restrict__ bias,
    u16* __restrict__ outB,
    const u16* __restrict__ GBb, const int* __restrict__ kidx,
    const float* __restrict__ bknn, u16* __restrict__ knn_bf) {
  __shared__ u16 As[128][72];
  __shared__ u16 Bs[128][72];
  int bid = blockIdx.x, tid = threadIdx.x;
  if (bid >= 192) {
    // ---- EdgeConv gather + leaky-relu + max over K=8 ----
    int wave = tid >> 6, lane = tid & 63;
    int row = (bid - 192) * 4 + wave;  // 0..8191
    int b = row >> 11, n = row & 2047;
    float base[6], acc[6];
#pragma unroll
    for (int j = 0; j < 6; j++) {
      int d = lane + 64 * j;
      base[j] = b2f(GBb[(size_t)row * 768 + 384 + d]) + bknn[d];
      acc[j] = -1e30f;
    }
    for (int kk = 0; kk < 8; kk++) {
      int g = kidx[(b * 8 + kk) * 2048 + n];
      const u16* Gr = GBb + (size_t)g * 768;
#pragma unroll
      for (int j = 0; j < 6; j++) {
        float v = b2f(Gr[lane + 64 * j]) + base[j];
        v = v > 0.f ? v : 0.2f * v;
        acc[j] = fmaxf(acc[j], v);
      }
    }
#pragma unroll
    for (int j = 0; j < 6; j++)
      knn_bf[(size_t)row * 384 + lane + 64 * j] = f2b(acc[j]);
    return;
  }
  // ---- proj: attn_bf = combine(OP0,OP1)/lsum @ wprojT + b_proj ----
  int lane = tid & 63, wave = tid >> 6, quad = lane >> 4, l16 = lane & 15;
  int n0 = (bid % 3) * 128, m0 = (bid / 3) * 128;
  int wm = (wave >> 1) * 64, wn = (wave & 1) * 64;
  floatx4 acc[4][4];
#pragma unroll
  for (int i = 0; i < 4; i++)
#pragma unroll
    for (int j = 0; j < 4; j++) acc[i][j] = zero4();

  for (int k0 = 0; k0 < 384; k0 += 64) {
#pragma unroll
    for (int i = 0; i < 4; i++) {
      int c = tid + 256 * i;
      int row = c >> 3, c8 = (c & 7) * 8;
      int gr = m0 + row;
      float rl = 1.f / (LS[gr] + LS[8192 + gr]);
      const u16* p0 = OPb + (size_t)gr * 384 + k0 + c8;
      sh8u a0, a1, pk;
      a0.v = *(const short8*)p0;
      a1.v = *(const short8*)(p0 + (size_t)8192 * 384);
#pragma unroll
      for (int j = 0; j < 8; j++) pk.u[j] = f2b((b2f(a0.u[j]) + b2f(a1.u[j])) * rl);
      *(short8*)&As[row][c8] = pk.v;
      *(short8*)&Bs[row][c8] =
          *(const short8*)(BwT + (size_t)(n0 + row) * 384 + k0 + c8);
    }
    __syncthreads();
#pragma unroll
    for (int kh = 0; kh < 2; kh++) {
      short8 af[4], bfr[4];
#pragma unroll
      for (int ti = 0; ti < 4; ti++)
        af[ti] = *(const short8*)&As[wm + ti * 16 + l16][kh * 32 + quad * 8];
#pragma unroll
      for (int tj = 0; tj < 4; tj++)
        bfr[tj] = *(const short8*)&Bs[wn + tj * 16 + l16][kh * 32 + quad * 8];
#pragma unroll
      for (int ti = 0; ti < 4; ti++)
#pragma unroll
        for (int tj = 0; tj < 4; tj++)
          acc[ti][tj] = mfma16(af[ti], bfr[tj], acc[ti][tj]);
    }
    __syncthreads();
  }
#pragma unroll
  for (int ti = 0; ti < 4; ti++)
#pragma unroll
    for (int tj = 0; tj < 4; tj++) {
      int col = n0 + wn + tj * 16 + l16;
      int row0 = m0 + wm + ti * 16 + quad * 4;
#pragma unroll
      for (int r = 0; r < 4; r++)
        outB[(size_t)(row0 + r) * 384 + col] = f2b(acc[ti][tj][r] + bias[col]);
    }
}

// ---------------- launch ----------------
extern "C" void kernel_launch(void* const* d_in, const int* in_sizes, int n_in,
                              void* d_out, int out_size, void* d_ws, size_t ws_size,
                              hipStream_t stream) {
  const float* x    = (const float*)d_in[0];
  const int* kidx   = (const int*)d_in[1];
  const float* ln1g = (const float*)d_in[2];
  const float* ln1b = (const float*)d_in[3];
  const float* wqkv = (const float*)d_in[4];
  const float* wproj= (const float*)d_in[5];
  const float* bproj= (const float*)d_in[6];
  const float* wknn = (const float*)d_in[7];
  const float* bknn = (const float*)d_in[8];
  const float* wg1  = (const float*)d_in[9];
  const float* bg1  = (const float*)d_in[10];
  const float* wg2  = (const float*)d_in[11];
  const float* bg2  = (const float*)d_in[12];
  const float* ln2g = (const float*)d_in[13];
  const float* ln2b = (const float*)d_in[14];
  const float* wfc1 = (const float*)d_in[15];
  const float* bfc1 = (const float*)d_in[16];
  const float* wfc2 = (const float*)d_in[17];
  const float* bfc2 = (const float*)d_in[18];
  float* out = (float*)d_out;

  const int M = 8192;
  char* ws = (char*)d_ws;
  size_t off = 0;
  auto alloc = [&](size_t bytes) -> char* {
    char* p = ws + off;
    off += (bytes + 255) & ~(size_t)255;
    return p;
  };
  u16* nx_bf    = (u16*)alloc((size_t)M * 384 * 2);
  u16* qkv_bf   = (u16*)alloc((size_t)M * 1152 * 2);   // + attn_bf reused as h_bf
  u16* attn_bf  = (u16*)alloc((size_t)M * 384 * 2);
  u16* GBb      = (u16*)alloc((size_t)M * 768 * 2);    // [G | base] bf16
  u16* knn_bf   = (u16*)alloc((size_t)M * 384 * 2);
  float* x2     = (float*)alloc((size_t)M * 384 * 4);
  u16* t1_bf    = (u16*)alloc((size_t)M * 384 * 2);
  u16* nx2_bf   = (u16*)alloc((size_t)M * 384 * 2);
  u16* Vt_b     = (u16*)alloc((size_t)24 * 64 * 2048 * 2);
  u16* OPb      = (u16*)alloc((size_t)2 * M * 384 * 2);  // attn split partials (bf16)
  float* LS     = (float*)alloc((size_t)2 * M * 4);
  u16* wqkvT    = (u16*)alloc((size_t)1152 * 384 * 2);
  u16* wprojT   = (u16*)alloc(384 * 384 * 2);
  u16* wcT      = (u16*)alloc((size_t)768 * 384 * 2);
  u16* wg1T     = (u16*)alloc((size_t)384 * 768 * 2);
  u16* wg2T     = (u16*)alloc(384 * 384 * 2);
  u16* wfc1T    = (u16*)alloc((size_t)1536 * 384 * 2);
  u16* wfc2T    = (u16*)alloc((size_t)384 * 1536 * 2);
  u16* h_bf     = qkv_bf;  // 8192x1536 bf16 over dead qkv(18.9MB)+attn_bf(6.3MB) regions

  // weight prep + LN1 (one fat launch)
  tcln_kernel<<<2660, 256, 0, stream>>>(wqkv, wproj, wg1, wg2, wfc1, wfc2, wknn,
                                        wqkvT, wprojT, wg1T, wg2T, wfc1T, wfc2T, wcT,
                                        x, ln1g, ln1b, nx_bf);
  // fused qkv + GB: [qkv | GBb] = nx @ [wqkvT | wcT]  (960 blocks)
  gemm128_kernel<8><<<dim3(15, 64), 256, 0, stream>>>(nx_bf, nx_bf, 384, wqkvT, wcT, 1920, 384,
                                                      nullptr, nullptr, qkv_bf, GBb,
                                                      nullptr, nullptr, nullptr, Vt_b);
  // attention: key-split=2, bf16 partials
  attn1_kernel<<<dim3(16, 24, 2), 256, 0, stream>>>(qkv_bf, Vt_b, OPb, LS);
  // proj (+fused split-combine) + knn (one fat launch)
  projknn_kernel<<<2240, 256, 0, stream>>>(OPb, LS, wprojT, bproj, attn_bf,
                                           GBb, kidx, bknn, knn_bf);
  // gate hidden: gelu([attn|knn] @ w_g1 + b_g1) -> bf16
  gemm128_kernel<3><<<dim3(3, 64), 256, 0, stream>>>(attn_bf, knn_bf, 384, wg1T, nullptr, 384, 768,
                                                     bg1, nullptr, t1_bf, nullptr,
                                                     nullptr, nullptr, nullptr, nullptr);
  // gate + fuse + residual: x2 = x + (1-g)*attn + g*knn
  gemm128_kernel<4><<<dim3(3, 64), 256, 0, stream>>>(t1_bf, t1_bf, 384, wg2T, nullptr, 384, 384,
                                                     bg2, x2, nullptr, nullptr,
                                                     attn_bf, knn_bf, x, nullptr);
  // LN2
  ln_kernel<<<2048, 256, 0, stream>>>(x2, ln2g, ln2b, nx2_bf);
  // fc1: gelu(nx2 @ w_fc1 + b_fc1) -> bf16
  gemm128_kernel<3><<<dim3(12, 64), 256, 0, stream>>>(nx2_bf, nx2_bf, 384, wfc1T, nullptr, 1536, 384,
                                                      bfc1, nullptr, h_bf, nullptr,
                                                      nullptr, nullptr, nullptr, nullptr);
  // fc2: out = x2 + h @ w_fc2 + b_fc2
  gemm128_kernel<5><<<dim3(3, 64), 256, 0, stream>>>(h_bf, h_bf, 1536, wfc2T, nullptr, 384, 1536,
                                                     bfc2, out, nullptr, nullptr,
                                                     nullptr, nullptr, x2, nullptr);
  (void)in_sizes; (void)n_in; (void)out_size; (void)ws_size;
}

// Round 8
// 313.682 us; speedup vs baseline: 1.4079x; 1.0024x over previous
//
#include <hip/hip_runtime.h>
#include <math.h>

typedef unsigned short u16;
typedef __attribute__((ext_vector_type(8))) short short8;
typedef __attribute__((ext_vector_type(4))) float floatx4;
typedef __attribute__((ext_vector_type(4))) short sh4v;

union sh4u { sh4v v; u16 u[4]; };
union sh8u { short8 v; u16 u[8]; };

__device__ __forceinline__ floatx4 mfma16(short8 a, short8 b, floatx4 c) {
  return __builtin_amdgcn_mfma_f32_16x16x32_bf16(a, b, c, 0, 0, 0);
}

__device__ __forceinline__ floatx4 zero4() {
  floatx4 z = {0.f, 0.f, 0.f, 0.f};
  return z;
}

__device__ __forceinline__ u16 f2b(float f) {
  union { float f; unsigned u; } v; v.f = f;
  unsigned u = v.u;
  return (u16)((u + 0x7FFFu + ((u >> 16) & 1u)) >> 16);
}

__device__ __forceinline__ float b2f(u16 u) {
  union { unsigned u; float f; } v; v.u = ((unsigned)u) << 16;
  return v.f;
}

__device__ __forceinline__ float gelu_exact(float x) {
  return 0.5f * x * (1.f + erff(x * 0.70710678118654752440f));
}

__device__ __forceinline__ unsigned pack2(float a, float b) {
  return (unsigned)f2b(a) | ((unsigned)f2b(b) << 16);
}

// truncating pack of two f32 -> two bf16 in one v_perm
__device__ __forceinline__ unsigned permpack(float p0, float p1) {
  return __builtin_amdgcn_perm(__float_as_uint(p1), __float_as_uint(p0), 0x07060302u);
}

// ------------- fat kernel: weight transpose-convert (blocks 0..611) + LN1 (612..2659) -------------
__global__ __launch_bounds__(256) void tcln_kernel(
    const float* __restrict__ p0, const float* __restrict__ p1,
    const float* __restrict__ p2, const float* __restrict__ p3,
    const float* __restrict__ p4, const float* __restrict__ p5,
    const float* __restrict__ wknn,
    u16* __restrict__ o0, u16* __restrict__ o1, u16* __restrict__ o2,
    u16* __restrict__ o3, u16* __restrict__ o4, u16* __restrict__ o5,
    u16* __restrict__ wcT,
    const float* __restrict__ x, const float* __restrict__ g,
    const float* __restrict__ bia, u16* __restrict__ nx) {
  __shared__ u16 L[64][66];
  int t = blockIdx.x, tid = threadIdx.x;
  if (t >= 612) {
    // ---- LN1: one wave per row ----
    int wave = tid >> 6, lane = tid & 63;
    int row = (t - 612) * 4 + wave;
    const float* xr = x + (size_t)row * 384;
    float v[6];
    float s = 0.f;
#pragma unroll
    for (int j = 0; j < 6; j++) { v[j] = xr[lane + 64 * j]; s += v[j]; }
#pragma unroll
    for (int off = 32; off > 0; off >>= 1) s += __shfl_xor(s, off);
    float mu = s * (1.f / 384.f);
    float ss = 0.f;
#pragma unroll
    for (int j = 0; j < 6; j++) { float d = v[j] - mu; ss += d * d; }
#pragma unroll
    for (int off = 32; off > 0; off >>= 1) ss += __shfl_xor(ss, off);
    float rstd = rsqrtf(ss * (1.f / 384.f) + 1e-5f);
    u16* orow = nx + (size_t)row * 384;
#pragma unroll
    for (int j = 0; j < 6; j++) {
      int d = lane + 64 * j;
      orow[d] = f2b((v[j] - mu) * rstd * g[d] + bia[d]);
    }
    return;
  }
  if (t >= 540) {
    t -= 540;                       // wcT: 6 k-tiles x 12 j-tiles
    int tk = t / 12, tn = t % 12;
    int k0 = tk * 64, j0 = tn * 64;
#pragma unroll
    for (int i = 0; i < 4; i++) {
      int c = tid + 256 * i;
      int r = c >> 4, c4 = (c & 15) * 4;
      floatx4 v;
      if (j0 < 384) {
        v = *(const floatx4*)(wknn + (size_t)(k0 + r) * 384 + j0 + c4);
      } else {
        floatx4 a = *(const floatx4*)(wknn + (size_t)(384 + k0 + r) * 384 + (j0 - 384) + c4);
        floatx4 b = *(const floatx4*)(wknn + (size_t)(k0 + r) * 384 + (j0 - 384) + c4);
        v = a - b;
      }
      *(unsigned*)&L[r][c4]     = pack2(v[0], v[1]);
      *(unsigned*)&L[r][c4 + 2] = pack2(v[2], v[3]);
    }
    __syncthreads();
#pragma unroll
    for (int i = 0; i < 2; i++) {
      int c = tid + 256 * i;
      int nn = c >> 3, k8 = (c & 7) * 8;
      sh8u pk;
#pragma unroll
      for (int j = 0; j < 8; j++) pk.u[j] = L[k8 + j][nn];
      *(short8*)(wcT + (size_t)(j0 + nn) * 384 + k0 + k8) = pk.v;
    }
    return;
  }
  const float* src; u16* dst; int Kd, Nd, tk, tn;
  if      (t < 108) { src = p0; dst = o0; Kd = 384;  Nd = 1152; tk = t / 18; tn = t % 18; }
  else if (t < 144) { src = p1; dst = o1; Kd = 384;  Nd = 384;  t -= 108; tk = t / 6;  tn = t % 6; }
  else if (t < 216) { src = p2; dst = o2; Kd = 768;  Nd = 384;  t -= 144; tk = t / 6;  tn = t % 6; }
  else if (t < 252) { src = p3; dst = o3; Kd = 384;  Nd = 384;  t -= 216; tk = t / 6;  tn = t % 6; }
  else if (t < 396) { src = p4; dst = o4; Kd = 384;  Nd = 1536; t -= 252; tk = t / 24; tn = t % 24; }
  else              { src = p5; dst = o5; Kd = 1536; Nd = 384;  t -= 396; tk = t / 6;  tn = t % 6; }
  int k0 = tk * 64, n0 = tn * 64;
#pragma unroll
  for (int i = 0; i < 4; i++) {
    int c = tid + 256 * i;
    int r = c >> 4, c4 = (c & 15) * 4;
    floatx4 v = *(const floatx4*)(src + (size_t)(k0 + r) * Nd + n0 + c4);
    *(unsigned*)&L[r][c4]     = pack2(v[0], v[1]);
    *(unsigned*)&L[r][c4 + 2] = pack2(v[2], v[3]);
  }
  __syncthreads();
#pragma unroll
  for (int i = 0; i < 2; i++) {
    int c = tid + 256 * i;
    int nn = c >> 3, k8 = (c & 7) * 8;
    sh8u pk;
#pragma unroll
    for (int j = 0; j < 8; j++) pk.u[j] = L[k8 + j][nn];
    *(short8*)(dst + (size_t)(n0 + nn) * Kd + k0 + k8) = pk.v;
  }
}

// ---------------- LayerNorm (bf16 in -> bf16 out), one wave per row of 384 ----------------
__global__ __launch_bounds__(256) void lnb_kernel(const u16* __restrict__ x,
                                                  const float* __restrict__ g,
                                                  const float* __restrict__ bia,
                                                  u16* __restrict__ out) {
  int wave = threadIdx.x >> 6, lane = threadIdx.x & 63;
  int row = blockIdx.x * 4 + wave;
  const u16* xr = x + (size_t)row * 384;
  float v[6];
  float s = 0.f;
#pragma unroll
  for (int j = 0; j < 6; j++) { v[j] = b2f(xr[lane + 64 * j]); s += v[j]; }
#pragma unroll
  for (int off = 32; off > 0; off >>= 1) s += __shfl_xor(s, off);
  float mu = s * (1.f / 384.f);
  float ss = 0.f;
#pragma unroll
  for (int j = 0; j < 6; j++) { float d = v[j] - mu; ss += d * d; }
#pragma unroll
  for (int off = 32; off > 0; off >>= 1) ss += __shfl_xor(ss, off);
  float rstd = rsqrtf(ss * (1.f / 384.f) + 1e-5f);
  u16* orow = out + (size_t)row * 384;
#pragma unroll
  for (int j = 0; j < 6; j++) {
    int d = lane + 64 * j;
    orow[d] = f2b((v[j] - mu) * rstd * g[d] + bia[d]);
  }
}

// ---------------- gemm128: 128x128 tile, BK=64, B pre-transposed, optional A concat ----------------
// EPI: 3 gelu(+bias) -> bf16 | 4 gate -> bf16 x2 | 7 +bias + bf16-resid -> f32
//      8 fused qkv+GB: n0<1152 -> qkv (Q pre-scale, V^T scatter), else GBb bf16
template <int EPI>
__global__ __launch_bounds__(256) void gemm128_kernel(
    const u16* __restrict__ A0, const u16* __restrict__ A1, int Ksplit,
    const u16* __restrict__ BwT, const u16* __restrict__ BwT2, int N, int K,
    const float* __restrict__ bias,
    float* __restrict__ outF, u16* __restrict__ outB, u16* __restrict__ outB2,
    const u16* __restrict__ eA16, const u16* __restrict__ eK16,
    const float* __restrict__ eX, u16* __restrict__ outV) {
  __shared__ u16 As[128][72];
  __shared__ u16 Bs[128][72];
  int tid = threadIdx.x;
  int lane = tid & 63, wave = tid >> 6, quad = lane >> 4, l16 = lane & 15;
  int n0 = blockIdx.x * 128, m0 = blockIdx.y * 128;
  int wm = (wave >> 1) * 64, wn = (wave & 1) * 64;
  const u16* Bsrc = BwT;
  int nbase = n0;
  if (EPI == 8 && n0 >= 1152) { Bsrc = BwT2; nbase = n0 - 1152; }
  floatx4 acc[4][4];
#pragma unroll
  for (int i = 0; i < 4; i++)
#pragma unroll
    for (int j = 0; j < 4; j++) acc[i][j] = zero4();

  for (int k0 = 0; k0 < K; k0 += 64) {
    const u16* Ap;
    int kk, sA;
    if (k0 < Ksplit) { Ap = A0; kk = k0; sA = Ksplit; }
    else             { Ap = A1; kk = k0 - Ksplit; sA = K - Ksplit; }
#pragma unroll
    for (int i = 0; i < 4; i++) {
      int c = tid + 256 * i;
      int row = c >> 3, c8 = (c & 7) * 8;
      *(short8*)&As[row][c8] =
          *(const short8*)(Ap + (size_t)(m0 + row) * sA + kk + c8);
      *(short8*)&Bs[row][c8] =
          *(const short8*)(Bsrc + (size_t)(nbase + row) * K + k0 + c8);
    }
    __syncthreads();
#pragma unroll
    for (int kh = 0; kh < 2; kh++) {
      short8 af[4], bfr[4];
#pragma unroll
      for (int ti = 0; ti < 4; ti++)
        af[ti] = *(const short8*)&As[wm + ti * 16 + l16][kh * 32 + quad * 8];
#pragma unroll
      for (int tj = 0; tj < 4; tj++)
        bfr[tj] = *(const short8*)&Bs[wn + tj * 16 + l16][kh * 32 + quad * 8];
#pragma unroll
      for (int ti = 0; ti < 4; ti++)
#pragma unroll
        for (int tj = 0; tj < 4; tj++)
          acc[ti][tj] = mfma16(af[ti], bfr[tj], acc[ti][tj]);
    }
    __syncthreads();
  }

#pragma unroll
  for (int ti = 0; ti < 4; ti++)
#pragma unroll
    for (int tj = 0; tj < 4; tj++) {
      int col = n0 + wn + tj * 16 + l16;
      int row0 = m0 + wm + ti * 16 + quad * 4;
      if (EPI == 8) {
        if (n0 < 1152) {
          float sc = (col < 384) ? 0.18033688011112042f : 1.f;  // Q * 0.125*log2(e)
          sh4u pk;
#pragma unroll
          for (int r = 0; r < 4; r++) {
            u16 bv = f2b(acc[ti][tj][r] * sc);
            outB[(size_t)(row0 + r) * 1152 + col] = bv;
            pk.u[r] = bv;
          }
          if (col >= 768) {
            int b = row0 >> 11, n = row0 & 2047;
            int hd = col - 768;
            *(sh4v*)(outV + ((size_t)(b * 6 + (hd >> 6)) * 64 + (hd & 63)) * 2048 + n) = pk.v;
          }
        } else {
#pragma unroll
          for (int r = 0; r < 4; r++)
            outB2[(size_t)(row0 + r) * 768 + (col - 1152)] = f2b(acc[ti][tj][r]);
        }
      } else {
#pragma unroll
        for (int r = 0; r < 4; r++) {
          size_t rc = (size_t)(row0 + r) * N + col;
          float v = acc[ti][tj][r];
          if (EPI == 3) {
            outB[rc] = f2b(gelu_exact(v + bias[col]));
          } else if (EPI == 4) {
            float gte = 1.f / (1.f + __expf(-(v + bias[col])));
            float fu = (1.f - gte) * b2f(eA16[rc]) + gte * b2f(eK16[rc]);
            outB[rc] = f2b(eX[rc] + fu);
          } else if (EPI == 7) {
            outF[rc] = v + bias[col] + b2f(eA16[rc]);
          }
        }
      }
    }
}

// ---------------- attention: 4 waves x 32 q-rows, key-split=4, bf16 partials ----------------
// grid (16 qtiles of 128, 24 bh, 4 splits), 256 thr. Q pre-scaled by 0.125*log2e.
__global__ __launch_bounds__(256) void attn1_kernel(const u16* __restrict__ qkv,
                                                    const u16* __restrict__ Vt,
                                                    u16* __restrict__ OPb,
                                                    float* __restrict__ LS) {
  __shared__ u16 Ks[64][72];    // K tile [key][dim]
  __shared__ u16 Vts[64][72];   // V^T tile [dim][key]
  __shared__ u16 Ps[4][32][72]; // per-wave P [qrow(32)][key]
  int tid = threadIdx.x;
  int lane = tid & 63, w = tid >> 6, quad = lane >> 4, l16 = lane & 15;
  int bh = blockIdx.y, b = bh / 6, h = bh % 6;
  int q0 = blockIdx.x * 128, split = blockIdx.z;
  const u16* qbase = qkv + (size_t)b * 2048 * 1152 + h * 64;
  const u16* kbase = qbase + 384 + (size_t)split * 512 * 1152;
  const u16* vtb = Vt + (size_t)bh * 64 * 2048 + split * 512;
  short8 qf[2][2];
#pragma unroll
  for (int s = 0; s < 2; s++) {
    int qrow = q0 + w * 32 + s * 16 + l16;
    qf[s][0] = *(const short8*)(qbase + (size_t)qrow * 1152 + quad * 8);
    qf[s][1] = *(const short8*)(qbase + (size_t)qrow * 1152 + 32 + quad * 8);
  }
  floatx4 O[4][2];
  float lsum[2] = {0.f, 0.f};
#pragma unroll
  for (int i = 0; i < 4; i++)
#pragma unroll
    for (int s = 0; s < 2; s++) O[i][s] = zero4();

  int rb = tid >> 3, c8 = (tid & 7) * 8;
  short8 rk[2], rv[2];
  rk[0] = *(const short8*)(kbase + (size_t)rb * 1152 + c8);
  rk[1] = *(const short8*)(kbase + (size_t)(rb + 32) * 1152 + c8);
  rv[0] = *(const short8*)(vtb + (size_t)rb * 2048 + c8);
  rv[1] = *(const short8*)(vtb + (size_t)(rb + 32) * 2048 + c8);

  for (int kt = 0; kt < 8; kt++) {
    __syncthreads();  // previous tile's frag reads done
    *(short8*)&Ks[rb][c8] = rk[0];
    *(short8*)&Ks[rb + 32][c8] = rk[1];
    *(short8*)&Vts[rb][c8] = rv[0];
    *(short8*)&Vts[rb + 32][c8] = rv[1];
    __syncthreads();
    if (kt < 7) {
      int key0 = (kt + 1) * 64;
      rk[0] = *(const short8*)(kbase + (size_t)(key0 + rb) * 1152 + c8);
      rk[1] = *(const short8*)(kbase + (size_t)(key0 + rb + 32) * 1152 + c8);
      rv[0] = *(const short8*)(vtb + (size_t)rb * 2048 + key0 + c8);
      rv[1] = *(const short8*)(vtb + (size_t)(rb + 32) * 2048 + key0 + c8);
    }
    // S^T: st = S^T[key=mt*16+quad*4+r][q = s*16+l16]
#pragma unroll
    for (int mt = 0; mt < 4; mt++) {
      short8 k0 = *(const short8*)&Ks[mt * 16 + l16][quad * 8];
      short8 k1 = *(const short8*)&Ks[mt * 16 + l16][32 + quad * 8];
#pragma unroll
      for (int s = 0; s < 2; s++) {
        floatx4 st = mfma16(k0, qf[s][0], zero4());
        st = mfma16(k1, qf[s][1], st);
        float p0 = exp2f(st[0]), p1 = exp2f(st[1]);
        float p2 = exp2f(st[2]), p3 = exp2f(st[3]);
        lsum[s] += (p0 + p1) + (p2 + p3);
        uint2 pk;
        pk.x = permpack(p0, p1);
        pk.y = permpack(p2, p3);
        *(uint2*)&Ps[w][s * 16 + l16][mt * 16 + quad * 4] = pk;
      }
    }
    // PV (intra-wave Ps, no barrier)
    short8 pf[2][2];
#pragma unroll
    for (int s = 0; s < 2; s++) {
      pf[s][0] = *(const short8*)&Ps[w][s * 16 + l16][quad * 8];
      pf[s][1] = *(const short8*)&Ps[w][s * 16 + l16][32 + quad * 8];
    }
#pragma unroll
    for (int mt2 = 0; mt2 < 4; mt2++) {
      short8 v0 = *(const short8*)&Vts[mt2 * 16 + l16][quad * 8];
      short8 v1 = *(const short8*)&Vts[mt2 * 16 + l16][32 + quad * 8];
#pragma unroll
      for (int s = 0; s < 2; s++) {
        O[mt2][s] = mfma16(v0, pf[s][0], O[mt2][s]);
        O[mt2][s] = mfma16(v1, pf[s][1], O[mt2][s]);
      }
    }
  }
  // per-split epilogue: unnormalized bf16 partials + f32 row-sum
#pragma unroll
  for (int s = 0; s < 2; s++) {
    lsum[s] += __shfl_xor(lsum[s], 16);
    lsum[s] += __shfl_xor(lsum[s], 32);
    int row = b * 2048 + q0 + w * 32 + s * 16 + l16;
    u16* orow = OPb + (size_t)split * 8192 * 384 + (size_t)row * 384 + h * 64;
#pragma unroll
    for (int mt2 = 0; mt2 < 4; mt2++) {
      sh4u pk;
#pragma unroll
      for (int r = 0; r < 4; r++) pk.u[r] = f2b(O[mt2][s][r]);
      *(sh4v*)(orow + mt2 * 16 + quad * 4) = pk.v;
    }
    if (quad == 0) LS[split * 8192 + row] = lsum[s];
  }
}

// ---------------- fat kernel: proj GEMM w/ fused 4-split-combine (0..191) + knn (192..2239) ----
__global__ __launch_bounds__(256) void projknn_kernel(
    const u16* __restrict__ OPb, const float* __restrict__ LS,
    const u16* __restrict__ BwT, const float* __restrict__ bias,
    u16* __restrict__ outB,
    const u16* __restrict__ GBb, const int* __restrict__ kidx,
    const float* __restrict__ bknn, u16* __restrict__ knn_bf) {
  __shared__ u16 As[128][72];
  __shared__ u16 Bs[128][72];
  int bid = blockIdx.x, tid = threadIdx.x;
  if (bid >= 192) {
    // ---- EdgeConv gather + leaky-relu + max over K=8 ----
    int wave = tid >> 6, lane = tid & 63;
    int row = (bid - 192) * 4 + wave;  // 0..8191
    int b = row >> 11, n = row & 2047;
    float base[6], acc[6];
#pragma unroll
    for (int j = 0; j < 6; j++) {
      int d = lane + 64 * j;
      base[j] = b2f(GBb[(size_t)row * 768 + 384 + d]) + bknn[d];
      acc[j] = -1e30f;
    }
    for (int kk = 0; kk < 8; kk++) {
      int g = kidx[(b * 8 + kk) * 2048 + n];
      const u16* Gr = GBb + (size_t)g * 768;
#pragma unroll
      for (int j = 0; j < 6; j++) {
        float v = b2f(Gr[lane + 64 * j]) + base[j];
        v = v > 0.f ? v : 0.2f * v;
        acc[j] = fmaxf(acc[j], v);
      }
    }
#pragma unroll
    for (int j = 0; j < 6; j++)
      knn_bf[(size_t)row * 384 + lane + 64 * j] = f2b(acc[j]);
    return;
  }
  // ---- proj: attn_bf = combine(OP0..OP3)/lsum @ wprojT + b_proj ----
  int lane = tid & 63, wave = tid >> 6, quad = lane >> 4, l16 = lane & 15;
  int n0 = (bid % 3) * 128, m0 = (bid / 3) * 128;
  int wm = (wave >> 1) * 64, wn = (wave & 1) * 64;
  floatx4 acc[4][4];
#pragma unroll
  for (int i = 0; i < 4; i++)
#pragma unroll
    for (int j = 0; j < 4; j++) acc[i][j] = zero4();

  const size_t SP = (size_t)8192 * 384;
  for (int k0 = 0; k0 < 384; k0 += 64) {
#pragma unroll
    for (int i = 0; i < 4; i++) {
      int c = tid + 256 * i;
      int row = c >> 3, c8 = (c & 7) * 8;
      int gr = m0 + row;
      float rl = 1.f / ((LS[gr] + LS[8192 + gr]) + (LS[16384 + gr] + LS[24576 + gr]));
      const u16* p0 = OPb + (size_t)gr * 384 + k0 + c8;
      sh8u a0, a1, a2, a3, pk;
      a0.v = *(const short8*)p0;
      a1.v = *(const short8*)(p0 + SP);
      a2.v = *(const short8*)(p0 + 2 * SP);
      a3.v = *(const short8*)(p0 + 3 * SP);
#pragma unroll
      for (int j = 0; j < 8; j++)
        pk.u[j] = f2b(((b2f(a0.u[j]) + b2f(a1.u[j])) + (b2f(a2.u[j]) + b2f(a3.u[j]))) * rl);
      *(short8*)&As[row][c8] = pk.v;
      *(short8*)&Bs[row][c8] =
          *(const short8*)(BwT + (size_t)(n0 + row) * 384 + k0 + c8);
    }
    __syncthreads();
#pragma unroll
    for (int kh = 0; kh < 2; kh++) {
      short8 af[4], bfr[4];
#pragma unroll
      for (int ti = 0; ti < 4; ti++)
        af[ti] = *(const short8*)&As[wm + ti * 16 + l16][kh * 32 + quad * 8];
#pragma unroll
      for (int tj = 0; tj < 4; tj++)
        bfr[tj] = *(const short8*)&Bs[wn + tj * 16 + l16][kh * 32 + quad * 8];
#pragma unroll
      for (int ti = 0; ti < 4; ti++)
#pragma unroll
        for (int tj = 0; tj < 4; tj++)
          acc[ti][tj] = mfma16(af[ti], bfr[tj], acc[ti][tj]);
    }
    __syncthreads();
  }
#pragma unroll
  for (int ti = 0; ti < 4; ti++)
#pragma unroll
    for (int tj = 0; tj < 4; tj++) {
      int col = n0 + wn + tj * 16 + l16;
      int row0 = m0 + wm + ti * 16 + quad * 4;
#pragma unroll
      for (int r = 0; r < 4; r++)
        outB[(size_t)(row0 + r) * 384 + col] = f2b(acc[ti][tj][r] + bias[col]);
    }
}

// ---------------- launch ----------------
extern "C" void kernel_launch(void* const* d_in, const int* in_sizes, int n_in,
                              void* d_out, int out_size, void* d_ws, size_t ws_size,
                              hipStream_t stream) {
  const float* x    = (const float*)d_in[0];
  const int* kidx   = (const int*)d_in[1];
  const float* ln1g = (const float*)d_in[2];
  const float* ln1b = (const float*)d_in[3];
  const float* wqkv = (const float*)d_in[4];
  const float* wproj= (const float*)d_in[5];
  const float* bproj= (const float*)d_in[6];
  const float* wknn = (const float*)d_in[7];
  const float* bknn = (const float*)d_in[8];
  const float* wg1  = (const float*)d_in[9];
  const float* bg1  = (const float*)d_in[10];
  const float* wg2  = (const float*)d_in[11];
  const float* bg2  = (const float*)d_in[12];
  const float* ln2g = (const float*)d_in[13];
  const float* ln2b = (const float*)d_in[14];
  const float* wfc1 = (const float*)d_in[15];
  const float* bfc1 = (const float*)d_in[16];
  const float* wfc2 = (const float*)d_in[17];
  const float* bfc2 = (const float*)d_in[18];
  float* out = (float*)d_out;

  const int M = 8192;
  char* ws = (char*)d_ws;
  size_t off = 0;
  auto alloc = [&](size_t bytes) -> char* {
    char* p = ws + off;
    off += (bytes + 255) & ~(size_t)255;
    return p;
  };
  u16* nx_bf    = (u16*)alloc((size_t)M * 384 * 2);
  u16* qkv_bf   = (u16*)alloc((size_t)M * 1152 * 2);   // + attn_bf reused as h_bf
  u16* attn_bf  = (u16*)alloc((size_t)M * 384 * 2);
  u16* GBb      = (u16*)alloc((size_t)M * 768 * 2);    // [G | base] bf16
  u16* knn_bf   = (u16*)alloc((size_t)M * 384 * 2);
  u16* x2b      = (u16*)alloc((size_t)M * 384 * 2);
  u16* t1_bf    = (u16*)alloc((size_t)M * 384 * 2);
  u16* nx2_bf   = (u16*)alloc((size_t)M * 384 * 2);
  u16* Vt_b     = (u16*)alloc((size_t)24 * 64 * 2048 * 2);
  u16* OPb      = (u16*)alloc((size_t)4 * M * 384 * 2);  // attn split partials (bf16)
  float* LS     = (float*)alloc((size_t)4 * M * 4);
  u16* wqkvT    = (u16*)alloc((size_t)1152 * 384 * 2);
  u16* wprojT   = (u16*)alloc(384 * 384 * 2);
  u16* wcT      = (u16*)alloc((size_t)768 * 384 * 2);
  u16* wg1T     = (u16*)alloc((size_t)384 * 768 * 2);
  u16* wg2T     = (u16*)alloc(384 * 384 * 2);
  u16* wfc1T    = (u16*)alloc((size_t)1536 * 384 * 2);
  u16* wfc2T    = (u16*)alloc((size_t)384 * 1536 * 2);
  u16* h_bf     = qkv_bf;  // 8192x1536 bf16 over dead qkv(18.9MB)+attn_bf(6.3MB) regions

  // weight prep + LN1 (one fat launch)
  tcln_kernel<<<2660, 256, 0, stream>>>(wqkv, wproj, wg1, wg2, wfc1, wfc2, wknn,
                                        wqkvT, wprojT, wg1T, wg2T, wfc1T, wfc2T, wcT,
                                        x, ln1g, ln1b, nx_bf);
  // fused qkv + GB: [qkv | GBb] = nx @ [wqkvT | wcT]  (960 blocks)
  gemm128_kernel<8><<<dim3(15, 64), 256, 0, stream>>>(nx_bf, nx_bf, 384, wqkvT, wcT, 1920, 384,
                                                      nullptr, nullptr, qkv_bf, GBb,
                                                      nullptr, nullptr, nullptr, Vt_b);
  // attention: key-split=4, bf16 partials
  attn1_kernel<<<dim3(16, 24, 4), 256, 0, stream>>>(qkv_bf, Vt_b, OPb, LS);
  // proj (+fused split-combine) + knn (one fat launch)
  projknn_kernel<<<2240, 256, 0, stream>>>(OPb, LS, wprojT, bproj, attn_bf,
                                           GBb, kidx, bknn, knn_bf);
  // gate hidden: gelu([attn|knn] @ w_g1 + b_g1) -> bf16
  gemm128_kernel<3><<<dim3(3, 64), 256, 0, stream>>>(attn_bf, knn_bf, 384, wg1T, nullptr, 384, 768,
                                                     bg1, nullptr, t1_bf, nullptr,
                                                     nullptr, nullptr, nullptr, nullptr);
  // gate + fuse + residual: x2b = bf16(x + (1-g)*attn + g*knn)
  gemm128_kernel<4><<<dim3(3, 64), 256, 0, stream>>>(t1_bf, t1_bf, 384, wg2T, nullptr, 384, 384,
                                                     bg2, nullptr, x2b, nullptr,
                                                     attn_bf, knn_bf, x, nullptr);
  // LN2 (bf16 in)
  lnb_kernel<<<2048, 256, 0, stream>>>(x2b, ln2g, ln2b, nx2_bf);
  // fc1: gelu(nx2 @ w_fc1 + b_fc1) -> bf16
  gemm128_kernel<3><<<dim3(12, 64), 256, 0, stream>>>(nx2_bf, nx2_bf, 384, wfc1T, nullptr, 1536, 384,
                                                      bfc1, nullptr, h_bf, nullptr,
                                                      nullptr, nullptr, nullptr, nullptr);
  // fc2: out = x2 + h @ w_fc2 + b_fc2
  gemm128_kernel<7><<<dim3(3, 64), 256, 0, stream>>>(h_bf, h_bf, 1536, wfc2T, nullptr, 384, 1536,
                                                     bfc2, out, nullptr, nullptr,
                                                     x2b, nullptr, nullptr, nullptr);
  (void)in_sizes; (void)n_in; (void)out_size; (void)ws_size;
}

// Round 9
// 297.800 us; speedup vs baseline: 1.4830x; 1.0533x over previous
//
#include <hip/hip_runtime.h>
#include <math.h>

typedef unsigned short u16;
typedef __attribute__((ext_vector_type(8))) short short8;
typedef __attribute__((ext_vector_type(4))) float floatx4;
typedef __attribute__((ext_vector_type(4))) short sh4v;

union sh4u { sh4v v; u16 u[4]; };
union sh8u { short8 v; u16 u[8]; };

__device__ __forceinline__ floatx4 mfma16(short8 a, short8 b, floatx4 c) {
  return __builtin_amdgcn_mfma_f32_16x16x32_bf16(a, b, c, 0, 0, 0);
}

__device__ __forceinline__ floatx4 zero4() {
  floatx4 z = {0.f, 0.f, 0.f, 0.f};
  return z;
}

__device__ __forceinline__ u16 f2b(float f) {
  union { float f; unsigned u; } v; v.f = f;
  unsigned u = v.u;
  return (u16)((u + 0x7FFFu + ((u >> 16) & 1u)) >> 16);
}

__device__ __forceinline__ float b2f(u16 u) {
  union { unsigned u; float f; } v; v.u = ((unsigned)u) << 16;
  return v.f;
}

__device__ __forceinline__ float gelu_exact(float x) {
  return 0.5f * x * (1.f + erff(x * 0.70710678118654752440f));
}

__device__ __forceinline__ unsigned pack2(float a, float b) {
  return (unsigned)f2b(a) | ((unsigned)f2b(b) << 16);
}

// truncating pack of two f32 -> two bf16 in one v_perm
__device__ __forceinline__ unsigned permpack(float p0, float p1) {
  return __builtin_amdgcn_perm(__float_as_uint(p1), __float_as_uint(p0), 0x07060302u);
}

// ------------- fat kernel: weight transpose-convert (blocks 0..611) + LN1 (612..2659) -------------
__global__ __launch_bounds__(256) void tcln_kernel(
    const float* __restrict__ p0, const float* __restrict__ p1,
    const float* __restrict__ p2, const float* __restrict__ p3,
    const float* __restrict__ p4, const float* __restrict__ p5,
    const float* __restrict__ wknn,
    u16* __restrict__ o0, u16* __restrict__ o1, u16* __restrict__ o2,
    u16* __restrict__ o3, u16* __restrict__ o4, u16* __restrict__ o5,
    u16* __restrict__ wcT,
    const float* __restrict__ x, const float* __restrict__ g,
    const float* __restrict__ bia, u16* __restrict__ nx) {
  __shared__ u16 L[64][66];
  int t = blockIdx.x, tid = threadIdx.x;
  if (t >= 612) {
    // ---- LN1: one wave per row ----
    int wave = tid >> 6, lane = tid & 63;
    int row = (t - 612) * 4 + wave;
    const float* xr = x + (size_t)row * 384;
    float v[6];
    float s = 0.f;
#pragma unroll
    for (int j = 0; j < 6; j++) { v[j] = xr[lane + 64 * j]; s += v[j]; }
#pragma unroll
    for (int off = 32; off > 0; off >>= 1) s += __shfl_xor(s, off);
    float mu = s * (1.f / 384.f);
    float ss = 0.f;
#pragma unroll
    for (int j = 0; j < 6; j++) { float d = v[j] - mu; ss += d * d; }
#pragma unroll
    for (int off = 32; off > 0; off >>= 1) ss += __shfl_xor(ss, off);
    float rstd = rsqrtf(ss * (1.f / 384.f) + 1e-5f);
    u16* orow = nx + (size_t)row * 384;
#pragma unroll
    for (int j = 0; j < 6; j++) {
      int d = lane + 64 * j;
      orow[d] = f2b((v[j] - mu) * rstd * g[d] + bia[d]);
    }
    return;
  }
  if (t >= 540) {
    t -= 540;                       // wcT: 6 k-tiles x 12 j-tiles
    int tk = t / 12, tn = t % 12;
    int k0 = tk * 64, j0 = tn * 64;
#pragma unroll
    for (int i = 0; i < 4; i++) {
      int c = tid + 256 * i;
      int r = c >> 4, c4 = (c & 15) * 4;
      floatx4 v;
      if (j0 < 384) {
        v = *(const floatx4*)(wknn + (size_t)(k0 + r) * 384 + j0 + c4);
      } else {
        floatx4 a = *(const floatx4*)(wknn + (size_t)(384 + k0 + r) * 384 + (j0 - 384) + c4);
        floatx4 b = *(const floatx4*)(wknn + (size_t)(k0 + r) * 384 + (j0 - 384) + c4);
        v = a - b;
      }
      *(unsigned*)&L[r][c4]     = pack2(v[0], v[1]);
      *(unsigned*)&L[r][c4 + 2] = pack2(v[2], v[3]);
    }
    __syncthreads();
#pragma unroll
    for (int i = 0; i < 2; i++) {
      int c = tid + 256 * i;
      int nn = c >> 3, k8 = (c & 7) * 8;
      sh8u pk;
#pragma unroll
      for (int j = 0; j < 8; j++) pk.u[j] = L[k8 + j][nn];
      *(short8*)(wcT + (size_t)(j0 + nn) * 384 + k0 + k8) = pk.v;
    }
    return;
  }
  const float* src; u16* dst; int Kd, Nd, tk, tn;
  if      (t < 108) { src = p0; dst = o0; Kd = 384;  Nd = 1152; tk = t / 18; tn = t % 18; }
  else if (t < 144) { src = p1; dst = o1; Kd = 384;  Nd = 384;  t -= 108; tk = t / 6;  tn = t % 6; }
  else if (t < 216) { src = p2; dst = o2; Kd = 768;  Nd = 384;  t -= 144; tk = t / 6;  tn = t % 6; }
  else if (t < 252) { src = p3; dst = o3; Kd = 384;  Nd = 384;  t -= 216; tk = t / 6;  tn = t % 6; }
  else if (t < 396) { src = p4; dst = o4; Kd = 384;  Nd = 1536; t -= 252; tk = t / 24; tn = t % 24; }
  else              { src = p5; dst = o5; Kd = 1536; Nd = 384;  t -= 396; tk = t / 6;  tn = t % 6; }
  int k0 = tk * 64, n0 = tn * 64;
#pragma unroll
  for (int i = 0; i < 4; i++) {
    int c = tid + 256 * i;
    int r = c >> 4, c4 = (c & 15) * 4;
    floatx4 v = *(const floatx4*)(src + (size_t)(k0 + r) * Nd + n0 + c4);
    *(unsigned*)&L[r][c4]     = pack2(v[0], v[1]);
    *(unsigned*)&L[r][c4 + 2] = pack2(v[2], v[3]);
  }
  __syncthreads();
#pragma unroll
  for (int i = 0; i < 2; i++) {
    int c = tid + 256 * i;
    int nn = c >> 3, k8 = (c & 7) * 8;
    sh8u pk;
#pragma unroll
    for (int j = 0; j < 8; j++) pk.u[j] = L[k8 + j][nn];
    *(short8*)(dst + (size_t)(n0 + nn) * Kd + k0 + k8) = pk.v;
  }
}

// ---------------- LayerNorm (bf16 in -> bf16 out), one wave per row of 384 ----------------
__global__ __launch_bounds__(256) void lnb_kernel(const u16* __restrict__ x,
                                                  const float* __restrict__ g,
                                                  const float* __restrict__ bia,
                                                  u16* __restrict__ out) {
  int wave = threadIdx.x >> 6, lane = threadIdx.x & 63;
  int row = blockIdx.x * 4 + wave;
  const u16* xr = x + (size_t)row * 384;
  float v[6];
  float s = 0.f;
#pragma unroll
  for (int j = 0; j < 6; j++) { v[j] = b2f(xr[lane + 64 * j]); s += v[j]; }
#pragma unroll
  for (int off = 32; off > 0; off >>= 1) s += __shfl_xor(s, off);
  float mu = s * (1.f / 384.f);
  float ss = 0.f;
#pragma unroll
  for (int j = 0; j < 6; j++) { float d = v[j] - mu; ss += d * d; }
#pragma unroll
  for (int off = 32; off > 0; off >>= 1) ss += __shfl_xor(ss, off);
  float rstd = rsqrtf(ss * (1.f / 384.f) + 1e-5f);
  u16* orow = out + (size_t)row * 384;
#pragma unroll
  for (int j = 0; j < 6; j++) {
    int d = lane + 64 * j;
    orow[d] = f2b((v[j] - mu) * rstd * g[d] + bia[d]);
  }
}

// ---------------- gemm128: 128x128 tile, BK=64, B pre-transposed ----------------
// EPI: 3 gelu(+bias) -> bf16 | 8 fused qkv+GB (Q pre-scale, V^T scatter / GBb)
template <int EPI>
__global__ __launch_bounds__(256) void gemm128_kernel(
    const u16* __restrict__ A0, const u16* __restrict__ BwT,
    const u16* __restrict__ BwT2, int N, int K,
    const float* __restrict__ bias, u16* __restrict__ outB, u16* __restrict__ outB2,
    u16* __restrict__ outV) {
  __shared__ u16 As[128][72];
  __shared__ u16 Bs[128][72];
  int tid = threadIdx.x;
  int lane = tid & 63, wave = tid >> 6, quad = lane >> 4, l16 = lane & 15;
  int n0 = blockIdx.x * 128, m0 = blockIdx.y * 128;
  int wm = (wave >> 1) * 64, wn = (wave & 1) * 64;
  const u16* Bsrc = BwT;
  int nbase = n0;
  if (EPI == 8 && n0 >= 1152) { Bsrc = BwT2; nbase = n0 - 1152; }
  floatx4 acc[4][4];
#pragma unroll
  for (int i = 0; i < 4; i++)
#pragma unroll
    for (int j = 0; j < 4; j++) acc[i][j] = zero4();

  for (int k0 = 0; k0 < K; k0 += 64) {
#pragma unroll
    for (int i = 0; i < 4; i++) {
      int c = tid + 256 * i;
      int row = c >> 3, c8 = (c & 7) * 8;
      *(short8*)&As[row][c8] =
          *(const short8*)(A0 + (size_t)(m0 + row) * K + k0 + c8);
      *(short8*)&Bs[row][c8] =
          *(const short8*)(Bsrc + (size_t)(nbase + row) * K + k0 + c8);
    }
    __syncthreads();
#pragma unroll
    for (int kh = 0; kh < 2; kh++) {
      short8 af[4], bfr[4];
#pragma unroll
      for (int ti = 0; ti < 4; ti++)
        af[ti] = *(const short8*)&As[wm + ti * 16 + l16][kh * 32 + quad * 8];
#pragma unroll
      for (int tj = 0; tj < 4; tj++)
        bfr[tj] = *(const short8*)&Bs[wn + tj * 16 + l16][kh * 32 + quad * 8];
#pragma unroll
      for (int ti = 0; ti < 4; ti++)
#pragma unroll
        for (int tj = 0; tj < 4; tj++)
          acc[ti][tj] = mfma16(af[ti], bfr[tj], acc[ti][tj]);
    }
    __syncthreads();
  }

#pragma unroll
  for (int ti = 0; ti < 4; ti++)
#pragma unroll
    for (int tj = 0; tj < 4; tj++) {
      int col = n0 + wn + tj * 16 + l16;
      int row0 = m0 + wm + ti * 16 + quad * 4;
      if (EPI == 8) {
        if (n0 < 1152) {
          float sc = (col < 384) ? 0.18033688011112042f : 1.f;  // Q * 0.125*log2(e)
          sh4u pk;
#pragma unroll
          for (int r = 0; r < 4; r++) {
            u16 bv = f2b(acc[ti][tj][r] * sc);
            outB[(size_t)(row0 + r) * 1152 + col] = bv;
            pk.u[r] = bv;
          }
          if (col >= 768) {
            int b = row0 >> 11, n = row0 & 2047;
            int hd = col - 768;
            *(sh4v*)(outV + ((size_t)(b * 6 + (hd >> 6)) * 64 + (hd & 63)) * 2048 + n) = pk.v;
          }
        } else {
#pragma unroll
          for (int r = 0; r < 4; r++)
            outB2[(size_t)(row0 + r) * 768 + (col - 1152)] = f2b(acc[ti][tj][r]);
        }
      } else {
#pragma unroll
        for (int r = 0; r < 4; r++)
          outB[(size_t)(row0 + r) * N + col] = f2b(gelu_exact(acc[ti][tj][r] + bias[col]));
      }
    }
}

// ---------------- gemm64: 64Mx128N tile, BK=64, reg-prefetch dbuf, 384-block grids ----------------
// EPI: 3 gelu(+bias) -> bf16 | 4 gate -> bf16 | 7 +bias + bf16-resid -> f32
template <int EPI>
__global__ __launch_bounds__(256) void gemm64_kernel(
    const u16* __restrict__ A0, const u16* __restrict__ A1, int Ksplit,
    const u16* __restrict__ BwT, int N, int K,
    const float* __restrict__ bias,
    float* __restrict__ outF, u16* __restrict__ outB,
    const u16* __restrict__ eA16, const u16* __restrict__ eK16,
    const float* __restrict__ eX) {
  __shared__ u16 As[64][72];
  __shared__ u16 Bs[128][72];
  int tid = threadIdx.x;
  int lane = tid & 63, w = tid >> 6, quad = lane >> 4, l16 = lane & 15;
  int n0 = blockIdx.x * 128, m0 = blockIdx.y * 64;
  int ra = tid >> 3, ca = (tid & 7) * 8;
  floatx4 acc[4][2];
#pragma unroll
  for (int i = 0; i < 4; i++)
#pragma unroll
    for (int j = 0; j < 2; j++) acc[i][j] = zero4();

  short8 pa[2], pb[4];
  auto loadAB = [&](int k0) {
    const u16* Ap;
    int kk, sA;
    if (k0 < Ksplit) { Ap = A0; kk = k0; sA = Ksplit; }
    else             { Ap = A1; kk = k0 - Ksplit; sA = K - Ksplit; }
    pa[0] = *(const short8*)(Ap + (size_t)(m0 + ra) * sA + kk + ca);
    pa[1] = *(const short8*)(Ap + (size_t)(m0 + ra + 32) * sA + kk + ca);
#pragma unroll
    for (int i = 0; i < 4; i++)
      pb[i] = *(const short8*)(BwT + (size_t)(n0 + ra + 32 * i) * K + k0 + ca);
  };
  loadAB(0);
  int iters = K >> 6;
  for (int kt = 0; kt < iters; kt++) {
    __syncthreads();
    *(short8*)&As[ra][ca] = pa[0];
    *(short8*)&As[ra + 32][ca] = pa[1];
#pragma unroll
    for (int i = 0; i < 4; i++) *(short8*)&Bs[ra + 32 * i][ca] = pb[i];
    __syncthreads();
    if (kt + 1 < iters) loadAB((kt + 1) * 64);
#pragma unroll
    for (int kh = 0; kh < 2; kh++) {
      short8 af[4], bfr[2];
#pragma unroll
      for (int mt = 0; mt < 4; mt++)
        af[mt] = *(const short8*)&As[mt * 16 + l16][kh * 32 + quad * 8];
#pragma unroll
      for (int nt = 0; nt < 2; nt++)
        bfr[nt] = *(const short8*)&Bs[w * 32 + nt * 16 + l16][kh * 32 + quad * 8];
#pragma unroll
      for (int mt = 0; mt < 4; mt++)
#pragma unroll
        for (int nt = 0; nt < 2; nt++)
          acc[mt][nt] = mfma16(af[mt], bfr[nt], acc[mt][nt]);
    }
  }

#pragma unroll
  for (int mt = 0; mt < 4; mt++)
#pragma unroll
    for (int nt = 0; nt < 2; nt++) {
      int col = n0 + w * 32 + nt * 16 + l16;
      int row0 = m0 + mt * 16 + quad * 4;
#pragma unroll
      for (int r = 0; r < 4; r++) {
        size_t rc = (size_t)(row0 + r) * N + col;
        float v = acc[mt][nt][r];
        if (EPI == 3) {
          outB[rc] = f2b(gelu_exact(v + bias[col]));
        } else if (EPI == 4) {
          float gte = 1.f / (1.f + __expf(-(v + bias[col])));
          float fu = (1.f - gte) * b2f(eA16[rc]) + gte * b2f(eK16[rc]);
          outB[rc] = f2b(eX[rc] + fu);
        } else if (EPI == 7) {
          outF[rc] = v + bias[col] + b2f(eA16[rc]);
        }
      }
    }
}

// ---------------- attention: 4 waves x 32 q-rows, key-split=4, lsum via ones-MFMA ----------------
// grid (16 qtiles of 128, 24 bh, 4 splits), 256 thr. Q pre-scaled by 0.125*log2e.
__global__ __launch_bounds__(256) void attn1_kernel(const u16* __restrict__ qkv,
                                                    const u16* __restrict__ Vt,
                                                    u16* __restrict__ OPb,
                                                    float* __restrict__ LS) {
  __shared__ u16 Ks[64][72];    // K tile [key][dim]
  __shared__ u16 Vts[64][72];   // V^T tile [dim][key]
  __shared__ u16 Ps[4][32][72]; // per-wave P [qrow(32)][key]
  int tid = threadIdx.x;
  int lane = tid & 63, w = tid >> 6, quad = lane >> 4, l16 = lane & 15;
  int bh = blockIdx.y, b = bh / 6, h = bh % 6;
  int q0 = blockIdx.x * 128, split = blockIdx.z;
  const u16* qbase = qkv + (size_t)b * 2048 * 1152 + h * 64;
  const u16* kbase = qbase + 384 + (size_t)split * 512 * 1152;
  const u16* vtb = Vt + (size_t)bh * 64 * 2048 + split * 512;
  short8 qf[2][2];
#pragma unroll
  for (int s = 0; s < 2; s++) {
    int qrow = q0 + w * 32 + s * 16 + l16;
    qf[s][0] = *(const short8*)(qbase + (size_t)qrow * 1152 + quad * 8);
    qf[s][1] = *(const short8*)(qbase + (size_t)qrow * 1152 + 32 + quad * 8);
  }
  short8 ones;
#pragma unroll
  for (int j = 0; j < 8; j++) ones[j] = (short)0x3F80;  // bf16 1.0
  floatx4 O[4][2];
  floatx4 accL[2] = {zero4(), zero4()};  // row-sum accumulator via ones-MFMA
#pragma unroll
  for (int i = 0; i < 4; i++)
#pragma unroll
    for (int s = 0; s < 2; s++) O[i][s] = zero4();

  int rb = tid >> 3, c8 = (tid & 7) * 8;
  short8 rk[2], rv[2];
  rk[0] = *(const short8*)(kbase + (size_t)rb * 1152 + c8);
  rk[1] = *(const short8*)(kbase + (size_t)(rb + 32) * 1152 + c8);
  rv[0] = *(const short8*)(vtb + (size_t)rb * 2048 + c8);
  rv[1] = *(const short8*)(vtb + (size_t)(rb + 32) * 2048 + c8);

  for (int kt = 0; kt < 8; kt++) {
    __syncthreads();  // previous tile's frag reads done
    *(short8*)&Ks[rb][c8] = rk[0];
    *(short8*)&Ks[rb + 32][c8] = rk[1];
    *(short8*)&Vts[rb][c8] = rv[0];
    *(short8*)&Vts[rb + 32][c8] = rv[1];
    __syncthreads();
    if (kt < 7) {
      int key0 = (kt + 1) * 64;
      rk[0] = *(const short8*)(kbase + (size_t)(key0 + rb) * 1152 + c8);
      rk[1] = *(const short8*)(kbase + (size_t)(key0 + rb + 32) * 1152 + c8);
      rv[0] = *(const short8*)(vtb + (size_t)rb * 2048 + key0 + c8);
      rv[1] = *(const short8*)(vtb + (size_t)(rb + 32) * 2048 + key0 + c8);
    }
    // S^T: st = S^T[key=mt*16+quad*4+r][q = s*16+l16]
#pragma unroll
    for (int mt = 0; mt < 4; mt++) {
      short8 k0 = *(const short8*)&Ks[mt * 16 + l16][quad * 8];
      short8 k1 = *(const short8*)&Ks[mt * 16 + l16][32 + quad * 8];
#pragma unroll
      for (int s = 0; s < 2; s++) {
        floatx4 st = mfma16(k0, qf[s][0], zero4());
        st = mfma16(k1, qf[s][1], st);
        uint2 pk;
        pk.x = permpack(exp2f(st[0]), exp2f(st[1]));
        pk.y = permpack(exp2f(st[2]), exp2f(st[3]));
        *(uint2*)&Ps[w][s * 16 + l16][mt * 16 + quad * 4] = pk;
      }
    }
    // PV + row-sum via ones-MFMA (intra-wave Ps, no barrier)
    short8 pf[2][2];
#pragma unroll
    for (int s = 0; s < 2; s++) {
      pf[s][0] = *(const short8*)&Ps[w][s * 16 + l16][quad * 8];
      pf[s][1] = *(const short8*)&Ps[w][s * 16 + l16][32 + quad * 8];
      accL[s] = mfma16(ones, pf[s][0], accL[s]);
      accL[s] = mfma16(ones, pf[s][1], accL[s]);
    }
#pragma unroll
    for (int mt2 = 0; mt2 < 4; mt2++) {
      short8 v0 = *(const short8*)&Vts[mt2 * 16 + l16][quad * 8];
      short8 v1 = *(const short8*)&Vts[mt2 * 16 + l16][32 + quad * 8];
#pragma unroll
      for (int s = 0; s < 2; s++) {
        O[mt2][s] = mfma16(v0, pf[s][0], O[mt2][s]);
        O[mt2][s] = mfma16(v1, pf[s][1], O[mt2][s]);
      }
    }
  }
  // per-split epilogue: unnormalized bf16 partials + f32 row-sum (accL rows all equal)
#pragma unroll
  for (int s = 0; s < 2; s++) {
    int row = b * 2048 + q0 + w * 32 + s * 16 + l16;
    u16* orow = OPb + (size_t)split * 8192 * 384 + (size_t)row * 384 + h * 64;
#pragma unroll
    for (int mt2 = 0; mt2 < 4; mt2++) {
      sh4u pk;
#pragma unroll
      for (int r = 0; r < 4; r++) pk.u[r] = f2b(O[mt2][s][r]);
      *(sh4v*)(orow + mt2 * 16 + quad * 4) = pk.v;
    }
    if (quad == 0) LS[split * 8192 + row] = accL[s][0];
  }
}

// ---------------- fat kernel: proj GEMM w/ fused 4-split-combine (0..191) + knn (192..2239) ----
__global__ __launch_bounds__(256) void projknn_kernel(
    const u16* __restrict__ OPb, const float* __restrict__ LS,
    const u16* __restrict__ BwT, const float* __restrict__ bias,
    u16* __restrict__ outB,
    const u16* __restrict__ GBb, const int* __restrict__ kidx,
    const float* __restrict__ bknn, u16* __restrict__ knn_bf) {
  __shared__ u16 As[128][72];
  __shared__ u16 Bs[128][72];
  int bid = blockIdx.x, tid = threadIdx.x;
  if (bid >= 192) {
    // ---- EdgeConv gather + leaky-relu + max over K=8 ----
    int wave = tid >> 6, lane = tid & 63;
    int row = (bid - 192) * 4 + wave;  // 0..8191
    int b = row >> 11, n = row & 2047;
    float base[6], acc[6];
#pragma unroll
    for (int j = 0; j < 6; j++) {
      int d = lane + 64 * j;
      base[j] = b2f(GBb[(size_t)row * 768 + 384 + d]) + bknn[d];
      acc[j] = -1e30f;
    }
    for (int kk = 0; kk < 8; kk++) {
      int g = kidx[(b * 8 + kk) * 2048 + n];
      const u16* Gr = GBb + (size_t)g * 768;
#pragma unroll
      for (int j = 0; j < 6; j++) {
        float v = b2f(Gr[lane + 64 * j]) + base[j];
        v = v > 0.f ? v : 0.2f * v;
        acc[j] = fmaxf(acc[j], v);
      }
    }
#pragma unroll
    for (int j = 0; j < 6; j++)
      knn_bf[(size_t)row * 384 + lane + 64 * j] = f2b(acc[j]);
    return;
  }
  // ---- proj: attn_bf = combine(OP0..OP3)/lsum @ wprojT + b_proj ----
  int lane = tid & 63, wave = tid >> 6, quad = lane >> 4, l16 = lane & 15;
  int n0 = (bid % 3) * 128, m0 = (bid / 3) * 128;
  int wm = (wave >> 1) * 64, wn = (wave & 1) * 64;
  floatx4 acc[4][4];
#pragma unroll
  for (int i = 0; i < 4; i++)
#pragma unroll
    for (int j = 0; j < 4; j++) acc[i][j] = zero4();

  const size_t SP = (size_t)8192 * 384;
  for (int k0 = 0; k0 < 384; k0 += 64) {
#pragma unroll
    for (int i = 0; i < 4; i++) {
      int c = tid + 256 * i;
      int row = c >> 3, c8 = (c & 7) * 8;
      int gr = m0 + row;
      float rl = 1.f / ((LS[gr] + LS[8192 + gr]) + (LS[16384 + gr] + LS[24576 + gr]));
      const u16* p0 = OPb + (size_t)gr * 384 + k0 + c8;
      sh8u a0, a1, a2, a3, pk;
      a0.v = *(const short8*)p0;
      a1.v = *(const short8*)(p0 + SP);
      a2.v = *(const short8*)(p0 + 2 * SP);
      a3.v = *(const short8*)(p0 + 3 * SP);
#pragma unroll
      for (int j = 0; j < 8; j++)
        pk.u[j] = f2b(((b2f(a0.u[j]) + b2f(a1.u[j])) + (b2f(a2.u[j]) + b2f(a3.u[j]))) * rl);
      *(short8*)&As[row][c8] = pk.v;
      *(short8*)&Bs[row][c8] =
          *(const short8*)(BwT + (size_t)(n0 + row) * 384 + k0 + c8);
    }
    __syncthreads();
#pragma unroll
    for (int kh = 0; kh < 2; kh++) {
      short8 af[4], bfr[4];
#pragma unroll
      for (int ti = 0; ti < 4; ti++)
        af[ti] = *(const short8*)&As[wm + ti * 16 + l16][kh * 32 + quad * 8];
#pragma unroll
      for (int tj = 0; tj < 4; tj++)
        bfr[tj] = *(const short8*)&Bs[wn + tj * 16 + l16][kh * 32 + quad * 8];
#pragma unroll
      for (int ti = 0; ti < 4; ti++)
#pragma unroll
        for (int tj = 0; tj < 4; tj++)
          acc[ti][tj] = mfma16(af[ti], bfr[tj], acc[ti][tj]);
    }
    __syncthreads();
  }
#pragma unroll
  for (int ti = 0; ti < 4; ti++)
#pragma unroll
    for (int tj = 0; tj < 4; tj++) {
      int col = n0 + wn + tj * 16 + l16;
      int row0 = m0 + wm + ti * 16 + quad * 4;
#pragma unroll
      for (int r = 0; r < 4; r++)
        outB[(size_t)(row0 + r) * 384 + col] = f2b(acc[ti][tj][r] + bias[col]);
    }
}

// ---------------- launch ----------------
extern "C" void kernel_launch(void* const* d_in, const int* in_sizes, int n_in,
                              void* d_out, int out_size, void* d_ws, size_t ws_size,
                              hipStream_t stream) {
  const float* x    = (const float*)d_in[0];
  const int* kidx   = (const int*)d_in[1];
  const float* ln1g = (const float*)d_in[2];
  const float* ln1b = (const float*)d_in[3];
  const float* wqkv = (const float*)d_in[4];
  const float* wproj= (const float*)d_in[5];
  const float* bproj= (const float*)d_in[6];
  const float* wknn = (const float*)d_in[7];
  const float* bknn = (const float*)d_in[8];
  const float* wg1  = (const float*)d_in[9];
  const float* bg1  = (const float*)d_in[10];
  const float* wg2  = (const float*)d_in[11];
  const float* bg2  = (const float*)d_in[12];
  const float* ln2g = (const float*)d_in[13];
  const float* ln2b = (const float*)d_in[14];
  const float* wfc1 = (const float*)d_in[15];
  const float* bfc1 = (const float*)d_in[16];
  const float* wfc2 = (const float*)d_in[17];
  const float* bfc2 = (const float*)d_in[18];
  float* out = (float*)d_out;

  const int M = 8192;
  char* ws = (char*)d_ws;
  size_t off = 0;
  auto alloc = [&](size_t bytes) -> char* {
    char* p = ws + off;
    off += (bytes + 255) & ~(size_t)255;
    return p;
  };
  u16* nx_bf    = (u16*)alloc((size_t)M * 384 * 2);
  u16* qkv_bf   = (u16*)alloc((size_t)M * 1152 * 2);   // + attn_bf reused as h_bf
  u16* attn_bf  = (u16*)alloc((size_t)M * 384 * 2);
  u16* GBb      = (u16*)alloc((size_t)M * 768 * 2);    // [G | base] bf16
  u16* knn_bf   = (u16*)alloc((size_t)M * 384 * 2);
  u16* x2b      = (u16*)alloc((size_t)M * 384 * 2);
  u16* t1_bf    = (u16*)alloc((size_t)M * 384 * 2);
  u16* nx2_bf   = (u16*)alloc((size_t)M * 384 * 2);
  u16* Vt_b     = (u16*)alloc((size_t)24 * 64 * 2048 * 2);
  u16* OPb      = (u16*)alloc((size_t)4 * M * 384 * 2);  // attn split partials (bf16)
  float* LS     = (float*)alloc((size_t)4 * M * 4);
  u16* wqkvT    = (u16*)alloc((size_t)1152 * 384 * 2);
  u16* wprojT   = (u16*)alloc(384 * 384 * 2);
  u16* wcT      = (u16*)alloc((size_t)768 * 384 * 2);
  u16* wg1T     = (u16*)alloc((size_t)384 * 768 * 2);
  u16* wg2T     = (u16*)alloc(384 * 384 * 2);
  u16* wfc1T    = (u16*)alloc((size_t)1536 * 384 * 2);
  u16* wfc2T    = (u16*)alloc((size_t)384 * 1536 * 2);
  u16* h_bf     = qkv_bf;  // 8192x1536 bf16 over dead qkv(18.9MB)+attn_bf(6.3MB) regions

  // weight prep + LN1 (one fat launch)
  tcln_kernel<<<2660, 256, 0, stream>>>(wqkv, wproj, wg1, wg2, wfc1, wfc2, wknn,
                                        wqkvT, wprojT, wg1T, wg2T, wfc1T, wfc2T, wcT,
                                        x, ln1g, ln1b, nx_bf);
  // fused qkv + GB: [qkv | GBb] = nx @ [wqkvT | wcT]  (960 blocks)
  gemm128_kernel<8><<<dim3(15, 64), 256, 0, stream>>>(nx_bf, wqkvT, wcT, 1920, 384,
                                                      nullptr, qkv_bf, GBb, Vt_b);
  // attention: key-split=4, bf16 partials, lsum via ones-MFMA
  attn1_kernel<<<dim3(16, 24, 4), 256, 0, stream>>>(qkv_bf, Vt_b, OPb, LS);
  // proj (+fused split-combine) + knn (one fat launch)
  projknn_kernel<<<2240, 256, 0, stream>>>(OPb, LS, wprojT, bproj, attn_bf,
                                           GBb, kidx, bknn, knn_bf);
  // gate hidden: gelu([attn|knn] @ w_g1 + b_g1) -> bf16  (384 blocks)
  gemm64_kernel<3><<<dim3(3, 128), 256, 0, stream>>>(attn_bf, knn_bf, 384, wg1T, 384, 768,
                                                     bg1, nullptr, t1_bf,
                                                     nullptr, nullptr, nullptr);
  // gate + fuse + residual: x2b = bf16(x + (1-g)*attn + g*knn)  (384 blocks)
  gemm64_kernel<4><<<dim3(3, 128), 256, 0, stream>>>(t1_bf, t1_bf, 384, wg2T, 384, 384,
                                                     bg2, nullptr, x2b,
                                                     attn_bf, knn_bf, x);
  // LN2 (bf16 in)
  lnb_kernel<<<2048, 256, 0, stream>>>(x2b, ln2g, ln2b, nx2_bf);
  // fc1: gelu(nx2 @ w_fc1 + b_fc1) -> bf16  (768 blocks)
  gemm128_kernel<3><<<dim3(12, 64), 256, 0, stream>>>(nx2_bf, wfc1T, nullptr, 1536, 384,
                                                      bfc1, h_bf, nullptr, nullptr);
  // fc2: out = x2 + h @ w_fc2 + b_fc2  (384 blocks)
  gemm64_kernel<7><<<dim3(3, 128), 256, 0, stream>>>(h_bf, h_bf, 1536, wfc2T, 384, 1536,
                                                     bfc2, out, nullptr,
                                                     x2b, nullptr, nullptr);
  (void)in_sizes; (void)n_in; (void)out_size; (void)ws_size;
}

// Round 10
// 278.608 us; speedup vs baseline: 1.5851x; 1.0689x over previous
//
#include <hip/hip_runtime.h>
#include <math.h>

typedef unsigned short u16;
typedef __attribute__((ext_vector_type(8))) short short8;
typedef __attribute__((ext_vector_type(4))) float floatx4;
typedef __attribute__((ext_vector_type(4))) short sh4v;

union sh4u { sh4v v; u16 u[4]; };
union sh8u { short8 v; u16 u[8]; };

__device__ __forceinline__ floatx4 mfma16(short8 a, short8 b, floatx4 c) {
  return __builtin_amdgcn_mfma_f32_16x16x32_bf16(a, b, c, 0, 0, 0);
}

__device__ __forceinline__ floatx4 zero4() {
  floatx4 z = {0.f, 0.f, 0.f, 0.f};
  return z;
}

__device__ __forceinline__ u16 f2b(float f) {
  union { float f; unsigned u; } v; v.f = f;
  unsigned u = v.u;
  return (u16)((u + 0x7FFFu + ((u >> 16) & 1u)) >> 16);
}

__device__ __forceinline__ float b2f(u16 u) {
  union { unsigned u; float f; } v; v.u = ((unsigned)u) << 16;
  return v.f;
}

__device__ __forceinline__ float gelu_exact(float x) {
  return 0.5f * x * (1.f + erff(x * 0.70710678118654752440f));
}

__device__ __forceinline__ unsigned pack2(float a, float b) {
  return (unsigned)f2b(a) | ((unsigned)f2b(b) << 16);
}

// truncating pack of two f32 -> two bf16 in one v_perm
__device__ __forceinline__ unsigned permpack(float p0, float p1) {
  return __builtin_amdgcn_perm(__float_as_uint(p1), __float_as_uint(p0), 0x07060302u);
}

// ------------- fat kernel: weight transpose-convert (blocks 0..611) + LN1 (612..2659) -------------
__global__ __launch_bounds__(256) void tcln_kernel(
    const float* __restrict__ p0, const float* __restrict__ p1,
    const float* __restrict__ p2, const float* __restrict__ p3,
    const float* __restrict__ p4, const float* __restrict__ p5,
    const float* __restrict__ wknn,
    u16* __restrict__ o0, u16* __restrict__ o1, u16* __restrict__ o2,
    u16* __restrict__ o3, u16* __restrict__ o4, u16* __restrict__ o5,
    u16* __restrict__ wcT,
    const float* __restrict__ x, const float* __restrict__ g,
    const float* __restrict__ bia, u16* __restrict__ nx) {
  __shared__ u16 L[64][66];
  int t = blockIdx.x, tid = threadIdx.x;
  if (t >= 612) {
    // ---- LN1: one wave per row ----
    int wave = tid >> 6, lane = tid & 63;
    int row = (t - 612) * 4 + wave;
    const float* xr = x + (size_t)row * 384;
    float v[6];
    float s = 0.f;
#pragma unroll
    for (int j = 0; j < 6; j++) { v[j] = xr[lane + 64 * j]; s += v[j]; }
#pragma unroll
    for (int off = 32; off > 0; off >>= 1) s += __shfl_xor(s, off);
    float mu = s * (1.f / 384.f);
    float ss = 0.f;
#pragma unroll
    for (int j = 0; j < 6; j++) { float d = v[j] - mu; ss += d * d; }
#pragma unroll
    for (int off = 32; off > 0; off >>= 1) ss += __shfl_xor(ss, off);
    float rstd = rsqrtf(ss * (1.f / 384.f) + 1e-5f);
    u16* orow = nx + (size_t)row * 384;
#pragma unroll
    for (int j = 0; j < 6; j++) {
      int d = lane + 64 * j;
      orow[d] = f2b((v[j] - mu) * rstd * g[d] + bia[d]);
    }
    return;
  }
  if (t >= 540) {
    t -= 540;                       // wcT: 6 k-tiles x 12 j-tiles
    int tk = t / 12, tn = t % 12;
    int k0 = tk * 64, j0 = tn * 64;
#pragma unroll
    for (int i = 0; i < 4; i++) {
      int c = tid + 256 * i;
      int r = c >> 4, c4 = (c & 15) * 4;
      floatx4 v;
      if (j0 < 384) {
        v = *(const floatx4*)(wknn + (size_t)(k0 + r) * 384 + j0 + c4);
      } else {
        floatx4 a = *(const floatx4*)(wknn + (size_t)(384 + k0 + r) * 384 + (j0 - 384) + c4);
        floatx4 b = *(const floatx4*)(wknn + (size_t)(k0 + r) * 384 + (j0 - 384) + c4);
        v = a - b;
      }
      *(unsigned*)&L[r][c4]     = pack2(v[0], v[1]);
      *(unsigned*)&L[r][c4 + 2] = pack2(v[2], v[3]);
    }
    __syncthreads();
#pragma unroll
    for (int i = 0; i < 2; i++) {
      int c = tid + 256 * i;
      int nn = c >> 3, k8 = (c & 7) * 8;
      sh8u pk;
#pragma unroll
      for (int j = 0; j < 8; j++) pk.u[j] = L[k8 + j][nn];
      *(short8*)(wcT + (size_t)(j0 + nn) * 384 + k0 + k8) = pk.v;
    }
    return;
  }
  const float* src; u16* dst; int Kd, Nd, tk, tn;
  if      (t < 108) { src = p0; dst = o0; Kd = 384;  Nd = 1152; tk = t / 18; tn = t % 18; }
  else if (t < 144) { src = p1; dst = o1; Kd = 384;  Nd = 384;  t -= 108; tk = t / 6;  tn = t % 6; }
  else if (t < 216) { src = p2; dst = o2; Kd = 768;  Nd = 384;  t -= 144; tk = t / 6;  tn = t % 6; }
  else if (t < 252) { src = p3; dst = o3; Kd = 384;  Nd = 384;  t -= 216; tk = t / 6;  tn = t % 6; }
  else if (t < 396) { src = p4; dst = o4; Kd = 384;  Nd = 1536; t -= 252; tk = t / 24; tn = t % 24; }
  else              { src = p5; dst = o5; Kd = 1536; Nd = 384;  t -= 396; tk = t / 6;  tn = t % 6; }
  int k0 = tk * 64, n0 = tn * 64;
#pragma unroll
  for (int i = 0; i < 4; i++) {
    int c = tid + 256 * i;
    int r = c >> 4, c4 = (c & 15) * 4;
    floatx4 v = *(const floatx4*)(src + (size_t)(k0 + r) * Nd + n0 + c4);
    *(unsigned*)&L[r][c4]     = pack2(v[0], v[1]);
    *(unsigned*)&L[r][c4 + 2] = pack2(v[2], v[3]);
  }
  __syncthreads();
#pragma unroll
  for (int i = 0; i < 2; i++) {
    int c = tid + 256 * i;
    int nn = c >> 3, k8 = (c & 7) * 8;
    sh8u pk;
#pragma unroll
    for (int j = 0; j < 8; j++) pk.u[j] = L[k8 + j][nn];
    *(short8*)(dst + (size_t)(n0 + nn) * Kd + k0 + k8) = pk.v;
  }
}

// ---------------- LayerNorm (bf16 in -> bf16 out), one wave per row of 384 ----------------
__global__ __launch_bounds__(256) void lnb_kernel(const u16* __restrict__ x,
                                                  const float* __restrict__ g,
                                                  const float* __restrict__ bia,
                                                  u16* __restrict__ out) {
  int wave = threadIdx.x >> 6, lane = threadIdx.x & 63;
  int row = blockIdx.x * 4 + wave;
  const u16* xr = x + (size_t)row * 384;
  float v[6];
  float s = 0.f;
#pragma unroll
  for (int j = 0; j < 6; j++) { v[j] = b2f(xr[lane + 64 * j]); s += v[j]; }
#pragma unroll
  for (int off = 32; off > 0; off >>= 1) s += __shfl_xor(s, off);
  float mu = s * (1.f / 384.f);
  float ss = 0.f;
#pragma unroll
  for (int j = 0; j < 6; j++) { float d = v[j] - mu; ss += d * d; }
#pragma unroll
  for (int off = 32; off > 0; off >>= 1) ss += __shfl_xor(ss, off);
  float rstd = rsqrtf(ss * (1.f / 384.f) + 1e-5f);
  u16* orow = out + (size_t)row * 384;
#pragma unroll
  for (int j = 0; j < 6; j++) {
    int d = lane + 64 * j;
    orow[d] = f2b((v[j] - mu) * rstd * g[d] + bia[d]);
  }
}

// ---------------- gemm64: 64Mx128N tile, BK=64, reg-prefetch dbuf ----------------
// EPI: 3 gelu(+bias) -> bf16 | 4 gate -> bf16 | 7 +bias + bf16-resid -> f32
//      8 fused qkv+GB: col<1152 -> qkv (Q pre-scale, V^T scatter), else GBb bf16
template <int EPI>
__global__ __launch_bounds__(256) void gemm64_kernel(
    const u16* __restrict__ A0, const u16* __restrict__ A1, int Ksplit,
    const u16* __restrict__ BwT, const u16* __restrict__ BwT2, int N, int K,
    const float* __restrict__ bias,
    float* __restrict__ outF, u16* __restrict__ outB, u16* __restrict__ outB2,
    const u16* __restrict__ eA16, const u16* __restrict__ eK16,
    const float* __restrict__ eX, u16* __restrict__ outV) {
  __shared__ u16 As[64][72];
  __shared__ u16 Bs[128][72];
  int tid = threadIdx.x;
  int lane = tid & 63, w = tid >> 6, quad = lane >> 4, l16 = lane & 15;
  int n0 = blockIdx.x * 128, m0 = blockIdx.y * 64;
  int ra = tid >> 3, ca = (tid & 7) * 8;
  const u16* Bsrc = BwT;
  int nbase = n0;
  if (EPI == 8 && n0 >= 1152) { Bsrc = BwT2; nbase = n0 - 1152; }
  floatx4 acc[4][2];
#pragma unroll
  for (int i = 0; i < 4; i++)
#pragma unroll
    for (int j = 0; j < 2; j++) acc[i][j] = zero4();

  short8 pa[2], pb[4];
  auto loadAB = [&](int k0) {
    const u16* Ap;
    int kk, sA;
    if (k0 < Ksplit) { Ap = A0; kk = k0; sA = Ksplit; }
    else             { Ap = A1; kk = k0 - Ksplit; sA = K - Ksplit; }
    pa[0] = *(const short8*)(Ap + (size_t)(m0 + ra) * sA + kk + ca);
    pa[1] = *(const short8*)(Ap + (size_t)(m0 + ra + 32) * sA + kk + ca);
#pragma unroll
    for (int i = 0; i < 4; i++)
      pb[i] = *(const short8*)(Bsrc + (size_t)(nbase + ra + 32 * i) * K + k0 + ca);
  };
  loadAB(0);
  int iters = K >> 6;
  for (int kt = 0; kt < iters; kt++) {
    __syncthreads();
    *(short8*)&As[ra][ca] = pa[0];
    *(short8*)&As[ra + 32][ca] = pa[1];
#pragma unroll
    for (int i = 0; i < 4; i++) *(short8*)&Bs[ra + 32 * i][ca] = pb[i];
    __syncthreads();
    if (kt + 1 < iters) loadAB((kt + 1) * 64);
#pragma unroll
    for (int kh = 0; kh < 2; kh++) {
      short8 af[4], bfr[2];
#pragma unroll
      for (int mt = 0; mt < 4; mt++)
        af[mt] = *(const short8*)&As[mt * 16 + l16][kh * 32 + quad * 8];
#pragma unroll
      for (int nt = 0; nt < 2; nt++)
        bfr[nt] = *(const short8*)&Bs[w * 32 + nt * 16 + l16][kh * 32 + quad * 8];
#pragma unroll
      for (int mt = 0; mt < 4; mt++)
#pragma unroll
        for (int nt = 0; nt < 2; nt++)
          acc[mt][nt] = mfma16(af[mt], bfr[nt], acc[mt][nt]);
    }
  }

#pragma unroll
  for (int mt = 0; mt < 4; mt++)
#pragma unroll
    for (int nt = 0; nt < 2; nt++) {
      int col = n0 + w * 32 + nt * 16 + l16;
      int row0 = m0 + mt * 16 + quad * 4;
      if (EPI == 8) {
        if (col < 1152) {
          float sc = (col < 384) ? 0.18033688011112042f : 1.f;  // Q * 0.125*log2(e)
          sh4u pk;
#pragma unroll
          for (int r = 0; r < 4; r++) {
            u16 bv = f2b(acc[mt][nt][r] * sc);
            outB[(size_t)(row0 + r) * 1152 + col] = bv;
            pk.u[r] = bv;
          }
          if (col >= 768) {
            int b = row0 >> 11, n = row0 & 2047;
            int hd = col - 768;
            *(sh4v*)(outV + ((size_t)(b * 6 + (hd >> 6)) * 64 + (hd & 63)) * 2048 + n) = pk.v;
          }
        } else {
#pragma unroll
          for (int r = 0; r < 4; r++)
            outB2[(size_t)(row0 + r) * 768 + (col - 1152)] = f2b(acc[mt][nt][r]);
        }
      } else {
#pragma unroll
        for (int r = 0; r < 4; r++) {
          size_t rc = (size_t)(row0 + r) * N + col;
          float v = acc[mt][nt][r];
          if (EPI == 3) {
            outB[rc] = f2b(gelu_exact(v + bias[col]));
          } else if (EPI == 4) {
            float gte = 1.f / (1.f + __expf(-(v + bias[col])));
            float fu = (1.f - gte) * b2f(eA16[rc]) + gte * b2f(eK16[rc]);
            outB[rc] = f2b(eX[rc] + fu);
          } else if (EPI == 7) {
            outF[rc] = v + bias[col] + b2f(eA16[rc]);
          }
        }
      }
    }
}

// ------- fat kernel: attention (blocks 0..1535, 4 splits) + EdgeConv knn (1536..3583) -------
// attn: 4 waves x 32 q-rows, key-split=4, lsum via ones-MFMA, bf16 partials.
__global__ __launch_bounds__(256) void attnknn_kernel(
    const u16* __restrict__ qkv, const u16* __restrict__ Vt,
    u16* __restrict__ OPb, float* __restrict__ LS,
    const u16* __restrict__ GBb, const int* __restrict__ kidx,
    const float* __restrict__ bknn, u16* __restrict__ knn_bf) {
  __shared__ u16 Ks[64][72];    // K tile [key][dim]
  __shared__ u16 Vts[64][72];   // V^T tile [dim][key]
  __shared__ u16 Ps[4][32][72]; // per-wave P [qrow(32)][key]
  int bid = blockIdx.x, tid = threadIdx.x;
  int lane = tid & 63, w = tid >> 6, quad = lane >> 4, l16 = lane & 15;
  if (bid >= 1536) {
    // ---- EdgeConv gather + leaky-relu + max over K=8 ----
    int row = (bid - 1536) * 4 + w;  // 0..8191
    int b = row >> 11, n = row & 2047;
    float base[6], acc[6];
#pragma unroll
    for (int j = 0; j < 6; j++) {
      int d = lane + 64 * j;
      base[j] = b2f(GBb[(size_t)row * 768 + 384 + d]) + bknn[d];
      acc[j] = -1e30f;
    }
    for (int kk = 0; kk < 8; kk++) {
      int g = kidx[(b * 8 + kk) * 2048 + n];
      const u16* Gr = GBb + (size_t)g * 768;
#pragma unroll
      for (int j = 0; j < 6; j++) {
        float v = b2f(Gr[lane + 64 * j]) + base[j];
        v = v > 0.f ? v : 0.2f * v;
        acc[j] = fmaxf(acc[j], v);
      }
    }
#pragma unroll
    for (int j = 0; j < 6; j++)
      knn_bf[(size_t)row * 384 + lane + 64 * j] = f2b(acc[j]);
    return;
  }
  int split = bid / 384;
  int rr = bid - split * 384;
  int bh = rr >> 4, b = bh / 6, h = bh % 6;
  int q0 = (rr & 15) * 128;
  const u16* qbase = qkv + (size_t)b * 2048 * 1152 + h * 64;
  const u16* kbase = qbase + 384 + (size_t)split * 512 * 1152;
  const u16* vtb = Vt + (size_t)bh * 64 * 2048 + split * 512;
  short8 qf[2][2];
#pragma unroll
  for (int s = 0; s < 2; s++) {
    int qrow = q0 + w * 32 + s * 16 + l16;
    qf[s][0] = *(const short8*)(qbase + (size_t)qrow * 1152 + quad * 8);
    qf[s][1] = *(const short8*)(qbase + (size_t)qrow * 1152 + 32 + quad * 8);
  }
  short8 ones;
#pragma unroll
  for (int j = 0; j < 8; j++) ones[j] = (short)0x3F80;  // bf16 1.0
  floatx4 O[4][2];
  floatx4 accL[2] = {zero4(), zero4()};  // row-sum accumulator via ones-MFMA
#pragma unroll
  for (int i = 0; i < 4; i++)
#pragma unroll
    for (int s = 0; s < 2; s++) O[i][s] = zero4();

  int rb = tid >> 3, c8 = (tid & 7) * 8;
  short8 rk[2], rv[2];
  rk[0] = *(const short8*)(kbase + (size_t)rb * 1152 + c8);
  rk[1] = *(const short8*)(kbase + (size_t)(rb + 32) * 1152 + c8);
  rv[0] = *(const short8*)(vtb + (size_t)rb * 2048 + c8);
  rv[1] = *(const short8*)(vtb + (size_t)(rb + 32) * 2048 + c8);

  for (int kt = 0; kt < 8; kt++) {
    __syncthreads();  // previous tile's frag reads done
    *(short8*)&Ks[rb][c8] = rk[0];
    *(short8*)&Ks[rb + 32][c8] = rk[1];
    *(short8*)&Vts[rb][c8] = rv[0];
    *(short8*)&Vts[rb + 32][c8] = rv[1];
    __syncthreads();
    if (kt < 7) {
      int key0 = (kt + 1) * 64;
      rk[0] = *(const short8*)(kbase + (size_t)(key0 + rb) * 1152 + c8);
      rk[1] = *(const short8*)(kbase + (size_t)(key0 + rb + 32) * 1152 + c8);
      rv[0] = *(const short8*)(vtb + (size_t)rb * 2048 + key0 + c8);
      rv[1] = *(const short8*)(vtb + (size_t)(rb + 32) * 2048 + key0 + c8);
    }
    // S^T: st = S^T[key=mt*16+quad*4+r][q = s*16+l16]
#pragma unroll
    for (int mt = 0; mt < 4; mt++) {
      short8 k0 = *(const short8*)&Ks[mt * 16 + l16][quad * 8];
      short8 k1 = *(const short8*)&Ks[mt * 16 + l16][32 + quad * 8];
#pragma unroll
      for (int s = 0; s < 2; s++) {
        floatx4 st = mfma16(k0, qf[s][0], zero4());
        st = mfma16(k1, qf[s][1], st);
        uint2 pk;
        pk.x = permpack(exp2f(st[0]), exp2f(st[1]));
        pk.y = permpack(exp2f(st[2]), exp2f(st[3]));
        *(uint2*)&Ps[w][s * 16 + l16][mt * 16 + quad * 4] = pk;
      }
    }
    // PV + row-sum via ones-MFMA (intra-wave Ps, no barrier)
    short8 pf[2][2];
#pragma unroll
    for (int s = 0; s < 2; s++) {
      pf[s][0] = *(const short8*)&Ps[w][s * 16 + l16][quad * 8];
      pf[s][1] = *(const short8*)&Ps[w][s * 16 + l16][32 + quad * 8];
      accL[s] = mfma16(ones, pf[s][0], accL[s]);
      accL[s] = mfma16(ones, pf[s][1], accL[s]);
    }
#pragma unroll
    for (int mt2 = 0; mt2 < 4; mt2++) {
      short8 v0 = *(const short8*)&Vts[mt2 * 16 + l16][quad * 8];
      short8 v1 = *(const short8*)&Vts[mt2 * 16 + l16][32 + quad * 8];
#pragma unroll
      for (int s = 0; s < 2; s++) {
        O[mt2][s] = mfma16(v0, pf[s][0], O[mt2][s]);
        O[mt2][s] = mfma16(v1, pf[s][1], O[mt2][s]);
      }
    }
  }
  // per-split epilogue: unnormalized bf16 partials + f32 row-sum (accL rows all equal)
#pragma unroll
  for (int s = 0; s < 2; s++) {
    int row = b * 2048 + q0 + w * 32 + s * 16 + l16;
    u16* orow = OPb + (size_t)split * 8192 * 384 + (size_t)row * 384 + h * 64;
#pragma unroll
    for (int mt2 = 0; mt2 < 4; mt2++) {
      sh4u pk;
#pragma unroll
      for (int r = 0; r < 4; r++) pk.u[r] = f2b(O[mt2][s][r]);
      *(sh4v*)(orow + mt2 * 16 + quad * 4) = pk.v;
    }
    if (quad == 0) LS[split * 8192 + row] = accL[s][0];
  }
}

// ---------------- proj: 64Mx128N GEMM on unnormalized split-sum, normalize in epilogue ----------------
__global__ __launch_bounds__(256) void projc_kernel(
    const u16* __restrict__ OPb, const float* __restrict__ LS,
    const u16* __restrict__ BwT, const float* __restrict__ bias,
    u16* __restrict__ outB) {
  __shared__ u16 As[64][72];
  __shared__ u16 Bs[128][72];
  int tid = threadIdx.x;
  int lane = tid & 63, w = tid >> 6, quad = lane >> 4, l16 = lane & 15;
  int n0 = blockIdx.x * 128, m0 = blockIdx.y * 64;
  int ra = tid >> 3, ca = (tid & 7) * 8;
  const size_t SP = (size_t)8192 * 384;
  floatx4 acc[4][2];
#pragma unroll
  for (int i = 0; i < 4; i++)
#pragma unroll
    for (int j = 0; j < 2; j++) acc[i][j] = zero4();

  short8 pa[2], pb[4];
  auto loadAB = [&](int k0) {
#pragma unroll
    for (int i = 0; i < 2; i++) {
      const u16* p = OPb + (size_t)(m0 + ra + 32 * i) * 384 + k0 + ca;
      sh8u a0, a1, a2, a3, pk;
      a0.v = *(const short8*)p;
      a1.v = *(const short8*)(p + SP);
      a2.v = *(const short8*)(p + 2 * SP);
      a3.v = *(const short8*)(p + 3 * SP);
#pragma unroll
      for (int j = 0; j < 8; j++)
        pk.u[j] = f2b((b2f(a0.u[j]) + b2f(a1.u[j])) + (b2f(a2.u[j]) + b2f(a3.u[j])));
      pa[i] = pk.v;
    }
#pragma unroll
    for (int i = 0; i < 4; i++)
      pb[i] = *(const short8*)(BwT + (size_t)(n0 + ra + 32 * i) * 384 + k0 + ca);
  };
  loadAB(0);
  for (int kt = 0; kt < 6; kt++) {
    __syncthreads();
    *(short8*)&As[ra][ca] = pa[0];
    *(short8*)&As[ra + 32][ca] = pa[1];
#pragma unroll
    for (int i = 0; i < 4; i++) *(short8*)&Bs[ra + 32 * i][ca] = pb[i];
    __syncthreads();
    if (kt < 5) loadAB((kt + 1) * 64);
#pragma unroll
    for (int kh = 0; kh < 2; kh++) {
      short8 af[4], bfr[2];
#pragma unroll
      for (int mt = 0; mt < 4; mt++)
        af[mt] = *(const short8*)&As[mt * 16 + l16][kh * 32 + quad * 8];
#pragma unroll
      for (int nt = 0; nt < 2; nt++)
        bfr[nt] = *(const short8*)&Bs[w * 32 + nt * 16 + l16][kh * 32 + quad * 8];
#pragma unroll
      for (int mt = 0; mt < 4; mt++)
#pragma unroll
        for (int nt = 0; nt < 2; nt++)
          acc[mt][nt] = mfma16(af[mt], bfr[nt], acc[mt][nt]);
    }
  }
#pragma unroll
  for (int mt = 0; mt < 4; mt++) {
    int row0 = m0 + mt * 16 + quad * 4;
    float rl[4];
#pragma unroll
    for (int r = 0; r < 4; r++) {
      int gr = row0 + r;
      rl[r] = 1.f / ((LS[gr] + LS[8192 + gr]) + (LS[16384 + gr] + LS[24576 + gr]));
    }
#pragma unroll
    for (int nt = 0; nt < 2; nt++) {
      int col = n0 + w * 32 + nt * 16 + l16;
#pragma unroll
      for (int r = 0; r < 4; r++)
        outB[(size_t)(row0 + r) * 384 + col] = f2b(acc[mt][nt][r] * rl[r] + bias[col]);
    }
  }
}

// ---------------- launch ----------------
extern "C" void kernel_launch(void* const* d_in, const int* in_sizes, int n_in,
                              void* d_out, int out_size, void* d_ws, size_t ws_size,
                              hipStream_t stream) {
  const float* x    = (const float*)d_in[0];
  const int* kidx   = (const int*)d_in[1];
  const float* ln1g = (const float*)d_in[2];
  const float* ln1b = (const float*)d_in[3];
  const float* wqkv = (const float*)d_in[4];
  const float* wproj= (const float*)d_in[5];
  const float* bproj= (const float*)d_in[6];
  const float* wknn = (const float*)d_in[7];
  const float* bknn = (const float*)d_in[8];
  const float* wg1  = (const float*)d_in[9];
  const float* bg1  = (const float*)d_in[10];
  const float* wg2  = (const float*)d_in[11];
  const float* bg2  = (const float*)d_in[12];
  const float* ln2g = (const float*)d_in[13];
  const float* ln2b = (const float*)d_in[14];
  const float* wfc1 = (const float*)d_in[15];
  const float* bfc1 = (const float*)d_in[16];
  const float* wfc2 = (const float*)d_in[17];
  const float* bfc2 = (const float*)d_in[18];
  float* out = (float*)d_out;

  const int M = 8192;
  char* ws = (char*)d_ws;
  size_t off = 0;
  auto alloc = [&](size_t bytes) -> char* {
    char* p = ws + off;
    off += (bytes + 255) & ~(size_t)255;
    return p;
  };
  u16* nx_bf    = (u16*)alloc((size_t)M * 384 * 2);
  u16* qkv_bf   = (u16*)alloc((size_t)M * 1152 * 2);   // + attn_bf reused as h_bf
  u16* attn_bf  = (u16*)alloc((size_t)M * 384 * 2);
  u16* GBb      = (u16*)alloc((size_t)M * 768 * 2);    // [G | base] bf16
  u16* knn_bf   = (u16*)alloc((size_t)M * 384 * 2);
  u16* x2b      = (u16*)alloc((size_t)M * 384 * 2);
  u16* t1_bf    = (u16*)alloc((size_t)M * 384 * 2);
  u16* nx2_bf   = (u16*)alloc((size_t)M * 384 * 2);
  u16* Vt_b     = (u16*)alloc((size_t)24 * 64 * 2048 * 2);
  u16* OPb      = (u16*)alloc((size_t)4 * M * 384 * 2);  // attn split partials (bf16)
  float* LS     = (float*)alloc((size_t)4 * M * 4);
  u16* wqkvT    = (u16*)alloc((size_t)1152 * 384 * 2);
  u16* wprojT   = (u16*)alloc(384 * 384 * 2);
  u16* wcT      = (u16*)alloc((size_t)768 * 384 * 2);
  u16* wg1T     = (u16*)alloc((size_t)384 * 768 * 2);
  u16* wg2T     = (u16*)alloc(384 * 384 * 2);
  u16* wfc1T    = (u16*)alloc((size_t)1536 * 384 * 2);
  u16* wfc2T    = (u16*)alloc((size_t)384 * 1536 * 2);
  u16* h_bf     = qkv_bf;  // 8192x1536 bf16 over dead qkv(18.9MB)+attn_bf(6.3MB) regions

  // weight prep + LN1 (one fat launch)
  tcln_kernel<<<2660, 256, 0, stream>>>(wqkv, wproj, wg1, wg2, wfc1, wfc2, wknn,
                                        wqkvT, wprojT, wg1T, wg2T, wfc1T, wfc2T, wcT,
                                        x, ln1g, ln1b, nx_bf);
  // fused qkv + GB: [qkv | GBb] = nx @ [wqkvT | wcT]  (1920 blocks)
  gemm64_kernel<8><<<dim3(15, 128), 256, 0, stream>>>(nx_bf, nx_bf, 384, wqkvT, wcT, 1920, 384,
                                                      nullptr, nullptr, qkv_bf, GBb,
                                                      nullptr, nullptr, nullptr, Vt_b);
  // attention (key-split=4, ones-MFMA lsum) + knn gather-max (one fat launch)
  attnknn_kernel<<<3584, 256, 0, stream>>>(qkv_bf, Vt_b, OPb, LS,
                                           GBb, kidx, bknn, knn_bf);
  // proj: combine(OP0..OP3) @ wprojT, normalize+bias in epilogue  (384 blocks)
  projc_kernel<<<dim3(3, 128), 256, 0, stream>>>(OPb, LS, wprojT, bproj, attn_bf);
  // gate hidden: gelu([attn|knn] @ w_g1 + b_g1) -> bf16  (384 blocks)
  gemm64_kernel<3><<<dim3(3, 128), 256, 0, stream>>>(attn_bf, knn_bf, 384, wg1T, nullptr, 384, 768,
                                                     bg1, nullptr, t1_bf, nullptr,
                                                     nullptr, nullptr, nullptr, nullptr);
  // gate + fuse + residual: x2b = bf16(x + (1-g)*attn + g*knn)  (384 blocks)
  gemm64_kernel<4><<<dim3(3, 128), 256, 0, stream>>>(t1_bf, t1_bf, 384, wg2T, nullptr, 384, 384,
                                                     bg2, nullptr, x2b, nullptr,
                                                     attn_bf, knn_bf, x, nullptr);
  // LN2 (bf16 in)
  lnb_kernel<<<2048, 256, 0, stream>>>(x2b, ln2g, ln2b, nx2_bf);
  // fc1: gelu(nx2 @ w_fc1 + b_fc1) -> bf16  (1536 blocks)
  gemm64_kernel<3><<<dim3(12, 128), 256, 0, stream>>>(nx2_bf, nx2_bf, 384, wfc1T, nullptr, 1536, 384,
                                                      bfc1, nullptr, h_bf, nullptr,
                                                      nullptr, nullptr, nullptr, nullptr);
  // fc2: out = x2 + h @ w_fc2 + b_fc2  (384 blocks)
  gemm64_kernel<7><<<dim3(3, 128), 256, 0, stream>>>(h_bf, h_bf, 1536, wfc2T, nullptr, 384, 1536,
                                                     bfc2, out, nullptr, nullptr,
                                                     x2b, nullptr, nullptr, nullptr);
  (void)in_sizes; (void)n_in; (void)out_size; (void)ws_size;
}